// Round 13
// baseline (1271.183 us; speedup 1.0000x reference)
//
#include <hip/hip_runtime.h>

// Problem constants
constexpr int cB = 32, cN = 512, cC = 64, cT = 24, cK = 3, cF = 64;
constexpr int cCT = cC * cT;   // 1536
constexpr int cFT = cF * cT;   // 1536

typedef __attribute__((ext_vector_type(8))) short s16x8;            // MFMA bf16 frag
typedef __attribute__((ext_vector_type(8))) unsigned short u16x8;   // 16B load/store
typedef __attribute__((ext_vector_type(4))) float f32x4;            // MFMA acc

__device__ inline unsigned short f2bf(float f) {
    union { float f; unsigned int u; } v; v.f = f;
    unsigned int r = v.u + 0x7FFFu + ((v.u >> 16) & 1u);
    return (unsigned short)(r >> 16);
}

// ---------------------------------------------------------------------------
__global__ __launch_bounds__(64) void k_spatial_lr(
    const float* __restrict__ x, const float* __restrict__ W1,
    const float* __restrict__ W2, const float* __restrict__ W3,
    float* __restrict__ lhs, float* __restrict__ rhs)
{
    int bn = blockIdx.x;
    int tid = threadIdx.x;
    __shared__ float xs[64][25];
    __shared__ float a_sh[64];
    const float* xp = x + (size_t)bn * cCT;
    for (int i = tid; i < cCT; i += 64) xs[i / cT][i % cT] = xp[i];
    __syncthreads();
    float s = 0.f;
    #pragma unroll
    for (int t = 0; t < cT; t++) s += xs[tid][t] * W1[t];
    a_sh[tid] = s;
    __syncthreads();
    if (tid < cT) {
        float l = 0.f, r = 0.f;
        for (int c = 0; c < cC; c++) {
            l += a_sh[c] * W2[c * cT + tid];
            r += xs[c][tid] * W3[c];
        }
        lhs[(size_t)bn * cT + tid] = l;
        rhs[(size_t)bn * cT + tid] = r;
    }
}

// ---------------------------------------------------------------------------
// Pt[b,n,m] = bf16(sigmoid(sum_t lhs[b,m,t]*rhs[b,n,t] + bs[m,n]))  (transposed)
__global__ __launch_bounds__(256) void k_product_t(
    const float* __restrict__ lhs, const float* __restrict__ rhs,
    const float* __restrict__ bs, unsigned short* __restrict__ Pt)
{
    int b = blockIdx.z;
    int m0 = blockIdx.y * 16, n0 = blockIdx.x * 16;
    int tx = threadIdx.x, ty = threadIdx.y;
    int tid = ty * 16 + tx;
    __shared__ float L[16][25], R[16][25], bss[16][17];
    for (int i = tid; i < 16 * cT; i += 256) {
        int r = i / cT, c = i % cT;
        L[r][c] = lhs[((size_t)b * cN + m0 + r) * cT + c];
        R[r][c] = rhs[((size_t)b * cN + n0 + r) * cT + c];
    }
    bss[tid >> 4][tid & 15] = bs[(size_t)(m0 + (tid >> 4)) * cN + n0 + (tid & 15)];
    __syncthreads();
    float s = 0.f;
    #pragma unroll
    for (int t = 0; t < cT; t++) s += L[tx][t] * R[ty][t];
    s += bss[tx][ty];
    float sig = 1.f / (1.f + expf(-s));
    Pt[((size_t)b * cN + n0 + ty) * cN + m0 + tx] = f2bf(sig);
}

// ---------------------------------------------------------------------------
// Batched bf16 MFMA GEMM, 128x128 tile, BK=32, 4 waves, 16x16x32 MFMA.
// Segmented K (512 per segment). Pass segA=segB=0 for K<=512.
template<int CM>
__global__ __launch_bounds__(256) void k_mfma_gemm(
    const unsigned short* __restrict__ A, int lda, long long aB, long long segA,
    const unsigned short* __restrict__ Bt, int ldb, long long bB, long long segB,
    void* __restrict__ Cv, int ldc, long long cBs,
    int K, int doAcc, int doRelu)
{
    __shared__ unsigned short As[128][40];
    __shared__ unsigned short Bs[128][40];
    int tid = threadIdx.x;
    int bn = blockIdx.x * 128;
    int bm = blockIdx.y * 128;
    int z  = blockIdx.z;
    const unsigned short* Ap = A  + (size_t)z * aB;
    const unsigned short* Bp = Bt + (size_t)z * bB;

    int lane = tid & 63, w = tid >> 6;
    int wm = (w >> 1) * 64, wn = (w & 1) * 64;
    int fr = lane & 15, kg = (lane >> 4) * 8;

    f32x4 acc[4][4] = {};

    int c0 = tid, c1 = tid + 256;
    int r0 = c0 >> 2, g0 = (c0 & 3) * 8;
    int r1 = c1 >> 2, g1 = (c1 & 3) * 8;

    for (int k0 = 0; k0 < K; k0 += 32) {
        int seg = k0 >> 9, off = k0 & 511;
        const unsigned short* Aseg = Ap + (size_t)seg * segA;
        const unsigned short* Bseg = Bp + (size_t)seg * segB;
        u16x8 a0 = *(const u16x8*)(Aseg + (size_t)(bm + r0) * lda + off + g0);
        u16x8 a1 = *(const u16x8*)(Aseg + (size_t)(bm + r1) * lda + off + g1);
        u16x8 b0 = *(const u16x8*)(Bseg + (size_t)(bn + r0) * ldb + off + g0);
        u16x8 b1 = *(const u16x8*)(Bseg + (size_t)(bn + r1) * ldb + off + g1);
        __syncthreads();
        *(u16x8*)&As[r0][g0] = a0;
        *(u16x8*)&As[r1][g1] = a1;
        *(u16x8*)&Bs[r0][g0] = b0;
        *(u16x8*)&Bs[r1][g1] = b1;
        __syncthreads();
        s16x8 af[4], bf[4];
        #pragma unroll
        for (int i = 0; i < 4; i++)
            af[i] = *(const s16x8*)&As[wm + i * 16 + fr][kg];
        #pragma unroll
        for (int j = 0; j < 4; j++)
            bf[j] = *(const s16x8*)&Bs[wn + j * 16 + fr][kg];
        #pragma unroll
        for (int i = 0; i < 4; i++)
            #pragma unroll
            for (int j = 0; j < 4; j++)
                acc[i][j] = __builtin_amdgcn_mfma_f32_16x16x32_bf16(
                    af[i], bf[j], acc[i][j], 0, 0, 0);
    }
    int rb = (lane >> 4) * 4;
    if (CM == 0) {
        float* Cp = (float*)Cv + (size_t)z * cBs;
        #pragma unroll
        for (int i = 0; i < 4; i++) {
            int row = bm + wm + i * 16 + rb;
            #pragma unroll
            for (int j = 0; j < 4; j++) {
                int col = bn + wn + j * 16 + fr;
                #pragma unroll
                for (int r = 0; r < 4; r++) {
                    size_t idx = (size_t)(row + r) * ldc + col;
                    float v = acc[i][j][r];
                    if (doAcc) v += Cp[idx];
                    if (doRelu) v = fmaxf(v, 0.f);
                    Cp[idx] = v;
                }
            }
        }
    } else {
        unsigned short* Cp = (unsigned short*)Cv + (size_t)z * cBs;
        #pragma unroll
        for (int i = 0; i < 4; i++) {
            int row = bm + wm + i * 16 + rb;
            #pragma unroll
            for (int j = 0; j < 4; j++) {
                int col = bn + wn + j * 16 + fr;
                #pragma unroll
                for (int r = 0; r < 4; r++)
                    Cp[(size_t)(row + r) * ldc + col] = f2bf(acc[i][j][r]);
            }
        }
    }
}

// ---------------------------------------------------------------------------
__global__ __launch_bounds__(256) void k_softmax512(float* __restrict__ S)
{
    int row = blockIdx.x;
    int tid = threadIdx.x;
    float* p = S + (size_t)row * cN;
    float v0 = p[tid], v1 = p[tid + 256];
    __shared__ float red[256];
    red[tid] = fmaxf(v0, v1);
    __syncthreads();
    for (int off = 128; off > 0; off >>= 1) {
        if (tid < off) red[tid] = fmaxf(red[tid], red[tid + off]);
        __syncthreads();
    }
    float mx = red[0];
    __syncthreads();
    float e0 = expf(v0 - mx), e1 = expf(v1 - mx);
    red[tid] = e0 + e1;
    __syncthreads();
    for (int off = 128; off > 0; off >>= 1) {
        if (tid < off) red[tid] += red[tid + off];
        __syncthreads();
    }
    float inv = 1.f / red[0];
    p[tid] = e0 * inv;
    p[tid + 256] = e1 * inv;
}

// ---------------------------------------------------------------------------
__global__ __launch_bounds__(256) void k_transpose_S(
    const float* __restrict__ S0, unsigned short* __restrict__ St)
{
    int b = blockIdx.z;
    int q0 = blockIdx.y * 64, n0 = blockIdx.x * 64;
    __shared__ float t[64][68];
    int tid = threadIdx.x;
    int r = tid >> 2, grp = (tid & 3) * 16;
    const float* ip = S0 + ((size_t)b * cN + q0 + r) * cN + n0 + grp;
    #pragma unroll
    for (int i = 0; i < 16; i += 4)
        *(float4*)&t[r][grp + i] = *(const float4*)(ip + i);
    __syncthreads();
    int nr = tid & 63, qg = (tid >> 6) * 16;
    unsigned short* op = St + ((size_t)b * cN + n0 + nr) * cN + q0 + qg;
    u16x8 v0, v1;
    #pragma unroll
    for (int i = 0; i < 8; i++) {
        v0[i] = f2bf(t[qg + i][nr]);
        v1[i] = f2bf(t[qg + 8 + i][nr]);
    }
    *(u16x8*)op = v0;
    *(u16x8*)(op + 8) = v1;
}

// ---------------------------------------------------------------------------
// xT2[z][t][n][c] = bf16(x[half*16+z][n][c][t])   (one pass per half)
__global__ __launch_bounds__(64) void k_xtrans_half(
    const float* __restrict__ x, int half, unsigned short* __restrict__ xT2)
{
    int idx = blockIdx.x;            // z*512 + n
    int z = idx >> 9, n = idx & 511;
    int b = half * 16 + z;
    int tid = threadIdx.x;
    __shared__ float xs[64][25];
    const float* xp = x + (size_t)(b * (size_t)cN + n) * cCT;
    for (int i = tid; i < cCT; i += 64) xs[i / cT][i % cT] = xp[i];
    __syncthreads();
    unsigned short* op = xT2 + (size_t)z * 786432 + (size_t)n * 64;
    for (int i = tid; i < cCT; i += 64) {
        int t = i >> 6, c = i & 63;
        op[(size_t)t * 32768 + c] = f2bf(xs[c][t]);
    }
}

// ---------------------------------------------------------------------------
// XT via MFMA, direct write to XTt[k][z][f*24+t][n].
__global__ __launch_bounds__(256) void k_xtheta_mfma(
    const unsigned short* __restrict__ xT2,   // [z][t][n][c]
    const unsigned short* __restrict__ ThT,   // [k][f][c]
    unsigned short* __restrict__ XTt,         // [k][z][f*24+t][n]
    long long segX)
{
    __shared__ unsigned short As[128][72];
    __shared__ unsigned short Ths[64][72];
    __shared__ unsigned short Cs[64][136];
    int tid = threadIdx.x;
    int n0 = blockIdx.x * 128;
    int t  = blockIdx.y;
    int z  = blockIdx.z;

    const unsigned short* ap = xT2 + (size_t)z * 786432 + (size_t)t * 32768 + n0 * 64;
    #pragma unroll
    for (int it = 0; it < 4; it++) {
        int v = tid + it * 256;
        int row = v >> 3, c8 = (v & 7) * 8;
        *(u16x8*)&As[row][c8] = *(const u16x8*)(ap + row * 64 + c8);
    }

    int lane = tid & 63, w = tid >> 6;
    int fr = lane & 15, kg = (lane >> 4) * 8;
    int rb = (lane >> 4) * 4;

    for (int k = 0; k < cK; k++) {
        __syncthreads();   // prev Cs/Ths reads + (k=0) A-stage done
        #pragma unroll
        for (int it = 0; it < 2; it++) {
            int vi = tid + it * 256;         // 0..511
            int row = vi >> 3, c8 = (vi & 7) * 8;
            *(u16x8*)&Ths[row][c8] =
                *(const u16x8*)(ThT + (size_t)k * 4096 + row * 64 + c8);
        }
        __syncthreads();
        f32x4 acc[2][4] = {};
        #pragma unroll
        for (int ks = 0; ks < 2; ks++) {
            s16x8 af[2], bf[4];
            #pragma unroll
            for (int i = 0; i < 2; i++)
                af[i] = *(const s16x8*)&As[w * 32 + i * 16 + fr][ks * 32 + kg];
            #pragma unroll
            for (int j = 0; j < 4; j++)
                bf[j] = *(const s16x8*)&Ths[j * 16 + fr][ks * 32 + kg];
            #pragma unroll
            for (int i = 0; i < 2; i++)
                #pragma unroll
                for (int j = 0; j < 4; j++)
                    acc[i][j] = __builtin_amdgcn_mfma_f32_16x16x32_bf16(
                        af[i], bf[j], acc[i][j], 0, 0, 0);
        }
        #pragma unroll
        for (int i = 0; i < 2; i++) {
            int rowb = w * 32 + i * 16 + rb;
            #pragma unroll
            for (int j = 0; j < 4; j++) {
                int f = j * 16 + fr;
                #pragma unroll
                for (int r = 0; r < 4; r++)
                    Cs[f][rowb + r] = f2bf(acc[i][j][r]);
            }
        }
        __syncthreads();
        unsigned short* op = XTt + (size_t)k * segX + (size_t)z * 786432 + n0;
        #pragma unroll
        for (int it = 0; it < 4; it++) {
            int v = tid + it * 256;
            int f = v >> 4, n8 = (v & 15) * 8;
            *(u16x8*)(op + (size_t)(f * 24 + t) * 512 + n8) = *(const u16x8*)&Cs[f][n8];
        }
    }
}

// ---------------------------------------------------------------------------
__global__ void k_convert(const float* __restrict__ a,
                          unsigned short* __restrict__ o, int n)
{
    int i = blockIdx.x * 256 + threadIdx.x;
    if (i < n) o[i] = f2bf(a[i]);
}

// ---------------------------------------------------------------------------
// W2g[f][d*64+fi] = bf16(conv_w[f][fi][0][d])
__global__ void k_wprep(const float* __restrict__ cw,
                        unsigned short* __restrict__ W2g)
{
    int i = blockIdx.x * 256 + threadIdx.x;
    if (i < 64 * 192) {
        int f = i / 192, k = i % 192;
        int d = k >> 6, fi = k & 63;
        W2g[i] = f2bf(cw[f * 192 + fi * 3 + d]);
    }
}

// ---------------------------------------------------------------------------
// ThT[k][f][c] = bf16(Theta[k][c][f])
__global__ void k_thprep(const float* __restrict__ Theta,
                         unsigned short* __restrict__ ThT)
{
    int i = blockIdx.x * 256 + threadIdx.x;
    if (i < cK * 64 * 64) {
        int k = i >> 12, r = i & 4095;
        int f = r >> 6, c = r & 63;
        ThT[i] = f2bf(Theta[k * 4096 + c * 64 + f]);
    }
}

// ---------------------------------------------------------------------------
__global__ __launch_bounds__(256) void k_hU1_part(
    const float* __restrict__ h, const float* __restrict__ U1,
    float* __restrict__ part)
{
    int b = blockIdx.x, nc = blockIdx.y;
    int tid = threadIdx.x;
    int f = tid & 63, q = tid >> 6;
    float acc[24];
    #pragma unroll
    for (int t = 0; t < 24; t++) acc[t] = 0.f;
    for (int n = nc * 32 + q; n < nc * 32 + 32; n += 4) {
        float u = U1[n];
        const float4* hp = (const float4*)(h + (((size_t)b * cN + n) * cF + f) * cT);
        #pragma unroll
        for (int v4 = 0; v4 < 6; v4++) {
            float4 hv = hp[v4];
            acc[v4 * 4 + 0] += u * hv.x;
            acc[v4 * 4 + 1] += u * hv.y;
            acc[v4 * 4 + 2] += u * hv.z;
            acc[v4 * 4 + 3] += u * hv.w;
        }
    }
    __shared__ float ps[4][64][25];
    #pragma unroll
    for (int t = 0; t < 24; t++) ps[q][f][t] = acc[t];
    __syncthreads();
    for (int i = tid; i < cFT; i += 256) {
        int f2 = i / cT, t2 = i % cT;
        float s = ps[0][f2][t2] + ps[1][f2][t2] + ps[2][f2][t2] + ps[3][f2][t2];
        part[(((size_t)b * 16 + nc) * cF + f2) * cT + t2] = s;
    }
}

// ---------------------------------------------------------------------------
__global__ __launch_bounds__(256) void k_lhs_t(
    const float* __restrict__ part, const float* __restrict__ U2,
    float* __restrict__ lhs_t)
{
    int b = blockIdx.x, ch = blockIdx.y;
    int tid = threadIdx.x;
    __shared__ float hu[1536];
    for (int i = tid; i < 1536; i += 256) {
        float s = 0.f;
        for (int nc = 0; nc < 16; nc++)
            s += part[((size_t)b * 16 + nc) * 1536 + i];
        hu[i] = s;
    }
    __syncthreads();
    int nn0 = ch * 128;
    for (int i = tid; i < cT * 128; i += 256) {
        int t = i / 128, nn = nn0 + (i % 128);
        float s = 0.f;
        #pragma unroll
        for (int f = 0; f < 64; f++) s += hu[f * cT + t] * U2[(size_t)f * cN + nn];
        lhs_t[((size_t)b * cT + t) * cN + nn] = s;
    }
}

// ---------------------------------------------------------------------------
__global__ __launch_bounds__(64) void k_rhs_t(
    const float* __restrict__ h, const float* __restrict__ U3,
    float* __restrict__ rhs_t)
{
    int bn = blockIdx.x;
    int f = threadIdx.x;
    __shared__ float sl[64][25];
    const float4* hp = (const float4*)(h + (size_t)bn * cFT + f * cT);
    float u = U3[f];
    #pragma unroll
    for (int v4 = 0; v4 < 6; v4++) {
        float4 hv = hp[v4];
        sl[f][v4 * 4 + 0] = u * hv.x;
        sl[f][v4 * 4 + 1] = u * hv.y;
        sl[f][v4 * 4 + 2] = u * hv.z;
        sl[f][v4 * 4 + 3] = u * hv.w;
    }
    __syncthreads();
    if (f < cT) {
        float s = 0.f;
        #pragma unroll
        for (int c = 0; c < 64; c++) s += sl[c][f];
        rhs_t[(size_t)bn * cT + f] = s;
    }
}

// ---------------------------------------------------------------------------
__global__ __launch_bounds__(576) void k_E(
    const float* __restrict__ lhs_t, const float* __restrict__ rhs_t,
    const float* __restrict__ be, const float* __restrict__ Ve,
    float* __restrict__ E)
{
    int b = blockIdx.x;
    int tid = threadIdx.x;
    int i = tid / 24, j = tid % 24;
    __shared__ float ps[24][25];
    __shared__ float er[24][25];
    __shared__ float mrow[24], srow[24];
    const float* lp = lhs_t + ((size_t)b * cT + i) * cN;
    const float* rp = rhs_t + (size_t)b * cN * cT;
    float s = 0.f;
    for (int n = 0; n < cN; n++) s += lp[n] * rp[n * cT + j];
    s += be[i * cT + j];
    ps[i][j] = 1.f / (1.f + expf(-s));
    __syncthreads();
    float e = 0.f;
    #pragma unroll
    for (int ss = 0; ss < cT; ss++) e += Ve[i * cT + ss] * ps[ss][j];
    er[i][j] = e;
    __syncthreads();
    if (j == 0) {
        float m = -1e30f;
        for (int r = 0; r < cT; r++) m = fmaxf(m, er[i][r]);
        float sm = 0.f;
        for (int r = 0; r < cT; r++) sm += expf(er[i][r] - m);
        mrow[i] = m;
        srow[i] = sm;
    }
    __syncthreads();
    E[(size_t)b * cT * cT + i * cT + j] = expf(er[i][j] - mrow[i]) / srow[i];
}

// ---------------------------------------------------------------------------
// FUSED: temporal mixing (h,E -> hT in LDS) + MFMA conv(1,3) + bias +
// residual(x) + LayerNorm over F, float4 stores. h and out alias d_out:
// each block reads rows n0..n0+7 (phase 1) then overwrites them (epilogue).
__global__ __launch_bounds__(256) void k_tmixconv(
    const float* h,                          // [b,n,f,t] f32 (aliases out)
    const float* __restrict__ E,             // [b][24][24]
    const float* __restrict__ x,             // [b,n,c,t] f32
    const unsigned short* __restrict__ W2g,  // [f][192] bf16, k=(d*64+fi)
    const float* __restrict__ cb,
    const float* __restrict__ lnw, const float* __restrict__ lnb,
    float* out)                              // [b,n,f,t] f32 (aliases h)
{
    __shared__ unsigned short Hs[8][26][72];
    __shared__ unsigned short Ws[64][200];
    __shared__ float Es[24][25];
    int tid = threadIdx.x;
    int blk = blockIdx.x;
    int b = blk >> 6;
    int n0 = (blk & 63) * 8;

    // stage Ws
    #pragma unroll
    for (int it = 0; it < 48; it++) {
        int i = tid + it * 256;
        Ws[i / 192][i % 192] = W2g[i];
    }
    // zero Hs halos (rows 0 and 25)
    if (tid < 144) {
        int s = tid / 18, rm = tid % 18;
        int side = rm / 9, c8 = (rm % 9) * 8;
        u16x8 z = {};
        *(u16x8*)&Hs[s][side * 25][c8] = z;
    }
    // stage E
    for (int i = tid; i < 576; i += 256)
        Es[i / 24][i % 24] = E[(size_t)b * 576 + i];
    __syncthreads();

    // ---- tmix phase: hT[s][t][f] = sum_t' h[s][f][t'] * E[t'][t] -> Hs
    #pragma unroll
    for (int pp = 0; pp < 2; pp++) {
        int p = tid + pp * 256;          // 0..511 = s*64+f
        int s = p >> 6, f = p & 63;
        const float4* hp4 =
            (const float4*)(h + (((size_t)b * cN + n0 + s) * 64 + f) * 24);
        float hv[24];
        #pragma unroll
        for (int v4 = 0; v4 < 6; v4++) {
            float4 v = hp4[v4];
            hv[v4 * 4 + 0] = v.x; hv[v4 * 4 + 1] = v.y;
            hv[v4 * 4 + 2] = v.z; hv[v4 * 4 + 3] = v.w;
        }
        #pragma unroll
        for (int so = 0; so < 24; so++) {
            float sacc = 0.f;
            #pragma unroll
            for (int t = 0; t < 24; t++) sacc += hv[t] * Es[t][so];
            Hs[s][1 + so][f] = f2bf(sacc);
        }
    }
    __syncthreads();

    // ---- conv MFMA phase (identical to round 12)
    int lane = tid & 63, w = tid >> 6;
    int fr = lane & 15, kgrp = lane >> 4;
    f32x4 acc[3][4] = {};

    int sA[3], tA[3];
    #pragma unroll
    for (int mi = 0; mi < 3; mi++) {
        int row = (w * 3 + mi) * 16 + fr;
        sA[mi] = row / 24; tA[mi] = row % 24;
    }
    #pragma unroll
    for (int ks = 0; ks < 6; ks++) {
        int d = ks >> 1;
        int fi0 = (ks & 1) * 32 + kgrp * 8;
        s16x8 bf[4];
        #pragma unroll
        for (int j = 0; j < 4; j++)
            bf[j] = *(const s16x8*)&Ws[j * 16 + fr][ks * 32 + kgrp * 8];
        #pragma unroll
        for (int mi = 0; mi < 3; mi++) {
            s16x8 af = *(const s16x8*)&Hs[sA[mi]][tA[mi] + d][fi0];
            #pragma unroll
            for (int j = 0; j < 4; j++)
                acc[mi][j] = __builtin_amdgcn_mfma_f32_16x16x32_bf16(
                    af, bf[j], acc[mi][j], 0, 0, 0);
        }
    }

    float lnw_v[4], lnb_v[4], cb_v[4];
    #pragma unroll
    for (int j = 0; j < 4; j++) {
        int f = j * 16 + fr;
        lnw_v[j] = lnw[f]; lnb_v[j] = lnb[f]; cb_v[j] = cb[f];
    }
    #pragma unroll
    for (int mi = 0; mi < 3; mi++) {
        int rowbase = (w * 3 + mi) * 16 + kgrp * 4;
        int sB = rowbase / 24, tb = rowbase % 24;
        size_t slab = ((size_t)b * cN + n0 + sB) * 64;
        float outv[4][4];   // [j][r]
        #pragma unroll
        for (int r = 0; r < 4; r++) {
            int t = tb + r;
            float v[4], s1 = 0.f, s2 = 0.f;
            #pragma unroll
            for (int j = 0; j < 4; j++) {
                float xres = x[(slab + j * 16 + fr) * 24 + t];
                v[j] = acc[mi][j][r] + cb_v[j] + xres;
                s1 += v[j];
                s2 += v[j] * v[j];
            }
            #pragma unroll
            for (int off = 1; off < 16; off <<= 1) {
                s1 += __shfl_xor(s1, off, 64);
                s2 += __shfl_xor(s2, off, 64);
            }
            float mean = s1 * (1.f / 64.f);
            float var = s2 * (1.f / 64.f) - mean * mean;
            float rstd = rsqrtf(var + 1e-5f);
            #pragma unroll
            for (int j = 0; j < 4; j++)
                outv[j][r] = (v[j] - mean) * rstd * lnw_v[j] + lnb_v[j];
        }
        #pragma unroll
        for (int j = 0; j < 4; j++) {
            float4 o = make_float4(outv[j][0], outv[j][1], outv[j][2], outv[j][3]);
            *(float4*)&out[(slab + j * 16 + fr) * 24 + tb] = o;
        }
    }
}

// ---------------------------------------------------------------------------
extern "C" void kernel_launch(void* const* d_in, const int* in_sizes, int n_in,
                              void* d_out, int out_size, void* d_ws, size_t ws_size,
                              hipStream_t stream)
{
    const float* x     = (const float*)d_in[0];
    const float* cheb  = (const float*)d_in[1];
    const float* W1    = (const float*)d_in[2];
    const float* W2    = (const float*)d_in[3];
    const float* W3    = (const float*)d_in[4];
    const float* bs    = (const float*)d_in[5];
    const float* Vs    = (const float*)d_in[6];
    const float* U1    = (const float*)d_in[7];
    const float* U2    = (const float*)d_in[8];
    const float* U3    = (const float*)d_in[9];
    const float* be    = (const float*)d_in[10];
    const float* Ve    = (const float*)d_in[11];
    const float* Theta = (const float*)d_in[12];
    const float* cw    = (const float*)d_in[13];
    const float* cbp   = (const float*)d_in[14];
    const float* lnw   = (const float*)d_in[15];
    const float* lnb   = (const float*)d_in[16];
    float* out = (float*)d_out;
    float* ws  = (float*)d_ws;

    // workspace layout: round-12 PASSING layout (peak 138.5 MB).
    unsigned short* Vs_bf   = (unsigned short*)(ws);              // 131072 f32
    unsigned short* cheb_bf = (unsigned short*)(ws + 131072);     // 393216 f32
    float*  lhs  = ws + 524288;     // 393216 (also lhs_t)
    float*  rhs  = ws + 917504;     // 393216 (also rhs_t)
    float*  part = ws + 1310720;    // 786432
    unsigned short* ThT = (unsigned short*)(ws + 1310720);        // overlays part (dead before part's first write)
    float*  Ebuf = ws + 2097152;    // 18432
    unsigned short* W2g = (unsigned short*)(ws + 2115584);        // 12288 u16 = 6144 f32
    unsigned short* St  = (unsigned short*)(ws + 2124800);        // 8388608 u16
    unsigned short* Wk  = (unsigned short*)(ws + 6319104);        // 12582912 u16
    unsigned short* XTt = (unsigned short*)(ws + 12610560);       // 37748736 u16 -> ends f32 31484928
    unsigned short* Pt  = (unsigned short*)(ws + 12610560);       // overlay (dead before XTt)
    float*          S0  = ws + 22047744;                          // 8388608 f32 (dead before XTt)
    unsigned short* xT2 = (unsigned short*)(ws + 31484928);       // 6291456 u16 (per half)

    const long long NN2 = (long long)cN * cN;        // 262144
    const long long NFT = (long long)cN * cFT;       // 786432
    const long long segW = 16LL * NN2;               // Wk k-segment (u16 elems)
    const long long segX = 16LL * 1536 * 512;        // XTt k-segment

    k_convert<<<1024, 256, 0, stream>>>(Vs, Vs_bf, 262144);
    k_convert<<<3072, 256, 0, stream>>>(cheb, cheb_bf, 786432);
    k_wprep<<<48, 256, 0, stream>>>(cw, W2g);
    k_thprep<<<48, 256, 0, stream>>>(Theta, ThT);

    // spatial attention
    k_spatial_lr<<<cB * cN, 64, 0, stream>>>(x, W1, W2, W3, lhs, rhs);
    k_product_t<<<dim3(32, 32, cB), dim3(16, 16), 0, stream>>>(lhs, rhs, bs, Pt);
    k_mfma_gemm<0><<<dim3(4, 4, cB), 256, 0, stream>>>(
        Vs_bf, 512, 0LL, 0LL, Pt, 512, NN2, 0LL, S0, 512, NN2, 512, 0, 0);
    k_softmax512<<<cB * cN, 256, 0, stream>>>(S0);
    k_transpose_S<<<dim3(8, 8, cB), 256, 0, stream>>>(S0, St);

    // Cheb conv, batch-halved with fused-K final GEMM -> h (f32, relu) in d_out
    for (int half = 0; half < 2; half++) {
        k_xtrans_half<<<16 * 512, 64, 0, stream>>>(x, half, xT2);
        k_xtheta_mfma<<<dim3(4, 24, 16), 256, 0, stream>>>(xT2, ThT, XTt, segX);
        for (int k = 0; k < cK; k++) {
            k_mfma_gemm<1><<<dim3(4, 4, 16), 256, 0, stream>>>(
                cheb_bf + (size_t)k * NN2, 512, 0LL, 0LL,
                St + (size_t)half * 16 * NN2, 512, NN2, 0LL,
                Wk + (size_t)k * segW, 512, NN2, 512, 0, 0);
        }
        k_mfma_gemm<0><<<dim3(12, 4, 16), 256, 0, stream>>>(
            Wk, 512, NN2, segW, XTt, 512, 786432LL, segX,
            out + (size_t)half * 16 * NFT, 1536, NFT, 1536, 0, 1);
    }

    // temporal attention (reads h = out f32; ThT dead from here)
    k_hU1_part<<<dim3(cB, 16), 256, 0, stream>>>(out, U1, part);
    k_rhs_t<<<cB * cN, 64, 0, stream>>>(out, U3, rhs);
    k_lhs_t<<<dim3(cB, 4), 256, 0, stream>>>(part, U2, lhs);
    k_E<<<cB, 576, 0, stream>>>(lhs, rhs, be, Ve, Ebuf);

    // fused temporal mixing + conv + LN: reads h (=out) + E + x, writes out
    k_tmixconv<<<2048, 256, 0, stream>>>(out, Ebuf, x, W2g, cbp, lnw, lnb, out);
}

// Round 14
// 602.946 us; speedup vs baseline: 2.1083x; 2.1083x over previous
//
#include <hip/hip_runtime.h>

// Problem constants
constexpr int cB = 32, cN = 512, cC = 64, cT = 24, cK = 3, cF = 64;
constexpr int cCT = cC * cT;   // 1536
constexpr int cFT = cF * cT;   // 1536

typedef __attribute__((ext_vector_type(8))) short s16x8;            // MFMA bf16 frag
typedef __attribute__((ext_vector_type(8))) unsigned short u16x8;   // 16B load/store
typedef __attribute__((ext_vector_type(4))) float f32x4;            // MFMA acc

__device__ inline unsigned short f2bf(float f) {
    union { float f; unsigned int u; } v; v.f = f;
    unsigned int r = v.u + 0x7FFFu + ((v.u >> 16) & 1u);
    return (unsigned short)(r >> 16);
}
__device__ inline float bf2f(unsigned short u) {
    union { unsigned int i; float f; } v; v.i = ((unsigned int)u) << 16;
    return v.f;
}

// ---------------------------------------------------------------------------
__global__ __launch_bounds__(64) void k_spatial_lr(
    const float* __restrict__ x, const float* __restrict__ W1,
    const float* __restrict__ W2, const float* __restrict__ W3,
    float* __restrict__ lhs, float* __restrict__ rhs)
{
    int bn = blockIdx.x;
    int tid = threadIdx.x;
    __shared__ float xs[64][25];
    __shared__ float a_sh[64];
    const float* xp = x + (size_t)bn * cCT;
    for (int i = tid; i < cCT; i += 64) xs[i / cT][i % cT] = xp[i];
    __syncthreads();
    float s = 0.f;
    #pragma unroll
    for (int t = 0; t < cT; t++) s += xs[tid][t] * W1[t];
    a_sh[tid] = s;
    __syncthreads();
    if (tid < cT) {
        float l = 0.f, r = 0.f;
        for (int c = 0; c < cC; c++) {
            l += a_sh[c] * W2[c * cT + tid];
            r += xs[c][tid] * W3[c];
        }
        lhs[(size_t)bn * cT + tid] = l;
        rhs[(size_t)bn * cT + tid] = r;
    }
}

// ---------------------------------------------------------------------------
// Pt[b,n,m] = bf16(sigmoid(sum_t lhs[b,m,t]*rhs[b,n,t] + bs[m,n]))  (transposed)
__global__ __launch_bounds__(256) void k_product_t(
    const float* __restrict__ lhs, const float* __restrict__ rhs,
    const float* __restrict__ bs, unsigned short* __restrict__ Pt)
{
    int b = blockIdx.z;
    int m0 = blockIdx.y * 16, n0 = blockIdx.x * 16;
    int tx = threadIdx.x, ty = threadIdx.y;
    int tid = ty * 16 + tx;
    __shared__ float L[16][25], R[16][25], bss[16][17];
    for (int i = tid; i < 16 * cT; i += 256) {
        int r = i / cT, c = i % cT;
        L[r][c] = lhs[((size_t)b * cN + m0 + r) * cT + c];
        R[r][c] = rhs[((size_t)b * cN + n0 + r) * cT + c];
    }
    bss[tid >> 4][tid & 15] = bs[(size_t)(m0 + (tid >> 4)) * cN + n0 + (tid & 15)];
    __syncthreads();
    float s = 0.f;
    #pragma unroll
    for (int t = 0; t < cT; t++) s += L[tx][t] * R[ty][t];
    s += bss[tx][ty];
    float sig = 1.f / (1.f + expf(-s));
    Pt[((size_t)b * cN + n0 + ty) * cN + m0 + tx] = f2bf(sig);
}

// ---------------------------------------------------------------------------
// Batched bf16 MFMA GEMM, 128x128 tile, BK=32, 4 waves, 16x16x32 MFMA.
// Segmented K (512 per segment). Pass segA=segB=0 for K<=512.
// CM==0: C f32 (doAcc/doRelu). CM==1: C bf16 (doRelu honored).
template<int CM>
__global__ __launch_bounds__(256) void k_mfma_gemm(
    const unsigned short* __restrict__ A, int lda, long long aB, long long segA,
    const unsigned short* __restrict__ Bt, int ldb, long long bB, long long segB,
    void* __restrict__ Cv, int ldc, long long cBs,
    int K, int doAcc, int doRelu)
{
    __shared__ unsigned short As[128][40];
    __shared__ unsigned short Bs[128][40];
    int tid = threadIdx.x;
    int bn = blockIdx.x * 128;
    int bm = blockIdx.y * 128;
    int z  = blockIdx.z;
    const unsigned short* Ap = A  + (size_t)z * aB;
    const unsigned short* Bp = Bt + (size_t)z * bB;

    int lane = tid & 63, w = tid >> 6;
    int wm = (w >> 1) * 64, wn = (w & 1) * 64;
    int fr = lane & 15, kg = (lane >> 4) * 8;

    f32x4 acc[4][4] = {};

    int c0 = tid, c1 = tid + 256;
    int r0 = c0 >> 2, g0 = (c0 & 3) * 8;
    int r1 = c1 >> 2, g1 = (c1 & 3) * 8;

    for (int k0 = 0; k0 < K; k0 += 32) {
        int seg = k0 >> 9, off = k0 & 511;
        const unsigned short* Aseg = Ap + (size_t)seg * segA;
        const unsigned short* Bseg = Bp + (size_t)seg * segB;
        u16x8 a0 = *(const u16x8*)(Aseg + (size_t)(bm + r0) * lda + off + g0);
        u16x8 a1 = *(const u16x8*)(Aseg + (size_t)(bm + r1) * lda + off + g1);
        u16x8 b0 = *(const u16x8*)(Bseg + (size_t)(bn + r0) * ldb + off + g0);
        u16x8 b1 = *(const u16x8*)(Bseg + (size_t)(bn + r1) * ldb + off + g1);
        __syncthreads();
        *(u16x8*)&As[r0][g0] = a0;
        *(u16x8*)&As[r1][g1] = a1;
        *(u16x8*)&Bs[r0][g0] = b0;
        *(u16x8*)&Bs[r1][g1] = b1;
        __syncthreads();
        s16x8 af[4], bf[4];
        #pragma unroll
        for (int i = 0; i < 4; i++)
            af[i] = *(const s16x8*)&As[wm + i * 16 + fr][kg];
        #pragma unroll
        for (int j = 0; j < 4; j++)
            bf[j] = *(const s16x8*)&Bs[wn + j * 16 + fr][kg];
        #pragma unroll
        for (int i = 0; i < 4; i++)
            #pragma unroll
            for (int j = 0; j < 4; j++)
                acc[i][j] = __builtin_amdgcn_mfma_f32_16x16x32_bf16(
                    af[i], bf[j], acc[i][j], 0, 0, 0);
    }
    int rb = (lane >> 4) * 4;
    if (CM == 0) {
        float* Cp = (float*)Cv + (size_t)z * cBs;
        #pragma unroll
        for (int i = 0; i < 4; i++) {
            int row = bm + wm + i * 16 + rb;
            #pragma unroll
            for (int j = 0; j < 4; j++) {
                int col = bn + wn + j * 16 + fr;
                #pragma unroll
                for (int r = 0; r < 4; r++) {
                    size_t idx = (size_t)(row + r) * ldc + col;
                    float v = acc[i][j][r];
                    if (doAcc) v += Cp[idx];
                    if (doRelu) v = fmaxf(v, 0.f);
                    Cp[idx] = v;
                }
            }
        }
    } else {
        unsigned short* Cp = (unsigned short*)Cv + (size_t)z * cBs;
        #pragma unroll
        for (int i = 0; i < 4; i++) {
            int row = bm + wm + i * 16 + rb;
            #pragma unroll
            for (int j = 0; j < 4; j++) {
                int col = bn + wn + j * 16 + fr;
                #pragma unroll
                for (int r = 0; r < 4; r++) {
                    float v = acc[i][j][r];
                    if (doRelu) v = fmaxf(v, 0.f);
                    Cp[(size_t)(row + r) * ldc + col] = f2bf(v);
                }
            }
        }
    }
}

// ---------------------------------------------------------------------------
__global__ __launch_bounds__(256) void k_softmax512(float* __restrict__ S)
{
    int row = blockIdx.x;
    int tid = threadIdx.x;
    float* p = S + (size_t)row * cN;
    float v0 = p[tid], v1 = p[tid + 256];
    __shared__ float red[256];
    red[tid] = fmaxf(v0, v1);
    __syncthreads();
    for (int off = 128; off > 0; off >>= 1) {
        if (tid < off) red[tid] = fmaxf(red[tid], red[tid + off]);
        __syncthreads();
    }
    float mx = red[0];
    __syncthreads();
    float e0 = expf(v0 - mx), e1 = expf(v1 - mx);
    red[tid] = e0 + e1;
    __syncthreads();
    for (int off = 128; off > 0; off >>= 1) {
        if (tid < off) red[tid] += red[tid + off];
        __syncthreads();
    }
    float inv = 1.f / red[0];
    p[tid] = e0 * inv;
    p[tid + 256] = e1 * inv;
}

// ---------------------------------------------------------------------------
__global__ __launch_bounds__(256) void k_transpose_S(
    const float* __restrict__ S0, unsigned short* __restrict__ St)
{
    int b = blockIdx.z;
    int q0 = blockIdx.y * 64, n0 = blockIdx.x * 64;
    __shared__ float t[64][68];
    int tid = threadIdx.x;
    int r = tid >> 2, grp = (tid & 3) * 16;
    const float* ip = S0 + ((size_t)b * cN + q0 + r) * cN + n0 + grp;
    #pragma unroll
    for (int i = 0; i < 16; i += 4)
        *(float4*)&t[r][grp + i] = *(const float4*)(ip + i);
    __syncthreads();
    int nr = tid & 63, qg = (tid >> 6) * 16;
    unsigned short* op = St + ((size_t)b * cN + n0 + nr) * cN + q0 + qg;
    u16x8 v0, v1;
    #pragma unroll
    for (int i = 0; i < 8; i++) {
        v0[i] = f2bf(t[qg + i][nr]);
        v1[i] = f2bf(t[qg + 8 + i][nr]);
    }
    *(u16x8*)op = v0;
    *(u16x8*)(op + 8) = v1;
}

// ---------------------------------------------------------------------------
// xT2[z][t][n][c] = bf16(x[half*16+z][n][c][t])   (one pass per half)
__global__ __launch_bounds__(64) void k_xtrans_half(
    const float* __restrict__ x, int half, unsigned short* __restrict__ xT2)
{
    int idx = blockIdx.x;            // z*512 + n
    int z = idx >> 9, n = idx & 511;
    int b = half * 16 + z;
    int tid = threadIdx.x;
    __shared__ float xs[64][25];
    const float* xp = x + (size_t)(b * (size_t)cN + n) * cCT;
    for (int i = tid; i < cCT; i += 64) xs[i / cT][i % cT] = xp[i];
    __syncthreads();
    unsigned short* op = xT2 + (size_t)z * 786432 + (size_t)n * 64;
    for (int i = tid; i < cCT; i += 64) {
        int t = i >> 6, c = i & 63;
        op[(size_t)t * 32768 + c] = f2bf(xs[c][t]);
    }
}

// ---------------------------------------------------------------------------
// XT via MFMA, direct write to XTt[k][z][f*24+t][n].
__global__ __launch_bounds__(256) void k_xtheta_mfma(
    const unsigned short* __restrict__ xT2,   // [z][t][n][c]
    const unsigned short* __restrict__ ThT,   // [k][f][c]
    unsigned short* __restrict__ XTt,         // [k][z][f*24+t][n]
    long long segX)
{
    __shared__ unsigned short As[128][72];
    __shared__ unsigned short Ths[64][72];
    __shared__ unsigned short Cs[64][136];
    int tid = threadIdx.x;
    int n0 = blockIdx.x * 128;
    int t  = blockIdx.y;
    int z  = blockIdx.z;

    const unsigned short* ap = xT2 + (size_t)z * 786432 + (size_t)t * 32768 + n0 * 64;
    #pragma unroll
    for (int it = 0; it < 4; it++) {
        int v = tid + it * 256;
        int row = v >> 3, c8 = (v & 7) * 8;
        *(u16x8*)&As[row][c8] = *(const u16x8*)(ap + row * 64 + c8);
    }

    int lane = tid & 63, w = tid >> 6;
    int fr = lane & 15, kg = (lane >> 4) * 8;
    int rb = (lane >> 4) * 4;

    for (int k = 0; k < cK; k++) {
        __syncthreads();   // prev Cs/Ths reads + (k=0) A-stage done
        #pragma unroll
        for (int it = 0; it < 2; it++) {
            int vi = tid + it * 256;         // 0..511
            int row = vi >> 3, c8 = (vi & 7) * 8;
            *(u16x8*)&Ths[row][c8] =
                *(const u16x8*)(ThT + (size_t)k * 4096 + row * 64 + c8);
        }
        __syncthreads();
        f32x4 acc[2][4] = {};
        #pragma unroll
        for (int ks = 0; ks < 2; ks++) {
            s16x8 af[2], bf[4];
            #pragma unroll
            for (int i = 0; i < 2; i++)
                af[i] = *(const s16x8*)&As[w * 32 + i * 16 + fr][ks * 32 + kg];
            #pragma unroll
            for (int j = 0; j < 4; j++)
                bf[j] = *(const s16x8*)&Ths[j * 16 + fr][ks * 32 + kg];
            #pragma unroll
            for (int i = 0; i < 2; i++)
                #pragma unroll
                for (int j = 0; j < 4; j++)
                    acc[i][j] = __builtin_amdgcn_mfma_f32_16x16x32_bf16(
                        af[i], bf[j], acc[i][j], 0, 0, 0);
        }
        #pragma unroll
        for (int i = 0; i < 2; i++) {
            int rowb = w * 32 + i * 16 + rb;
            #pragma unroll
            for (int j = 0; j < 4; j++) {
                int f = j * 16 + fr;
                #pragma unroll
                for (int r = 0; r < 4; r++)
                    Cs[f][rowb + r] = f2bf(acc[i][j][r]);
            }
        }
        __syncthreads();
        unsigned short* op = XTt + (size_t)k * segX + (size_t)z * 786432 + n0;
        #pragma unroll
        for (int it = 0; it < 4; it++) {
            int v = tid + it * 256;
            int f = v >> 4, n8 = (v & 15) * 8;
            *(u16x8*)(op + (size_t)(f * 24 + t) * 512 + n8) = *(const u16x8*)&Cs[f][n8];
        }
    }
}

// ---------------------------------------------------------------------------
__global__ void k_convert(const float* __restrict__ a,
                          unsigned short* __restrict__ o, int n)
{
    int i = blockIdx.x * 256 + threadIdx.x;
    if (i < n) o[i] = f2bf(a[i]);
}

// ---------------------------------------------------------------------------
// W2g[f][d*64+fi] = bf16(conv_w[f][fi][0][d])
__global__ void k_wprep(const float* __restrict__ cw,
                        unsigned short* __restrict__ W2g)
{
    int i = blockIdx.x * 256 + threadIdx.x;
    if (i < 64 * 192) {
        int f = i / 192, k = i % 192;
        int d = k >> 6, fi = k & 63;
        W2g[i] = f2bf(cw[f * 192 + fi * 3 + d]);
    }
}

// ---------------------------------------------------------------------------
// ThT[k][f][c] = bf16(Theta[k][c][f])
__global__ void k_thprep(const float* __restrict__ Theta,
                         unsigned short* __restrict__ ThT)
{
    int i = blockIdx.x * 256 + threadIdx.x;
    if (i < cK * 64 * 64) {
        int k = i >> 12, r = i & 4095;
        int f = r >> 6, c = r & 63;
        ThT[i] = f2bf(Theta[k * 4096 + c * 64 + f]);
    }
}

// ---------------------------------------------------------------------------
// partial hU1 from bf16 h
__global__ __launch_bounds__(256) void k_hU1_part(
    const unsigned short* __restrict__ h, const float* __restrict__ U1,
    float* __restrict__ part)
{
    int b = blockIdx.x, nc = blockIdx.y;
    int tid = threadIdx.x;
    int f = tid & 63, q = tid >> 6;
    float acc[24];
    #pragma unroll
    for (int t = 0; t < 24; t++) acc[t] = 0.f;
    for (int n = nc * 32 + q; n < nc * 32 + 32; n += 4) {
        float u = U1[n];
        const u16x8* hp = (const u16x8*)(h + (((size_t)b * cN + n) * cF + f) * cT);
        #pragma unroll
        for (int v8 = 0; v8 < 3; v8++) {
            u16x8 hv = hp[v8];
            #pragma unroll
            for (int e = 0; e < 8; e++)
                acc[v8 * 8 + e] += u * bf2f(hv[e]);
        }
    }
    __shared__ float ps[4][64][25];
    #pragma unroll
    for (int t = 0; t < 24; t++) ps[q][f][t] = acc[t];
    __syncthreads();
    for (int i = tid; i < cFT; i += 256) {
        int f2 = i / cT, t2 = i % cT;
        float s = ps[0][f2][t2] + ps[1][f2][t2] + ps[2][f2][t2] + ps[3][f2][t2];
        part[(((size_t)b * 16 + nc) * cF + f2) * cT + t2] = s;
    }
}

// ---------------------------------------------------------------------------
__global__ __launch_bounds__(256) void k_lhs_t(
    const float* __restrict__ part, const float* __restrict__ U2,
    float* __restrict__ lhs_t)
{
    int b = blockIdx.x, ch = blockIdx.y;
    int tid = threadIdx.x;
    __shared__ float hu[1536];
    for (int i = tid; i < 1536; i += 256) {
        float s = 0.f;
        for (int nc = 0; nc < 16; nc++)
            s += part[((size_t)b * 16 + nc) * 1536 + i];
        hu[i] = s;
    }
    __syncthreads();
    int nn0 = ch * 128;
    for (int i = tid; i < cT * 128; i += 256) {
        int t = i / 128, nn = nn0 + (i % 128);
        float s = 0.f;
        #pragma unroll
        for (int f = 0; f < 64; f++) s += hu[f * cT + t] * U2[(size_t)f * cN + nn];
        lhs_t[((size_t)b * cT + t) * cN + nn] = s;
    }
}

// ---------------------------------------------------------------------------
// rhs_t from bf16 h
__global__ __launch_bounds__(64) void k_rhs_t(
    const unsigned short* __restrict__ h, const float* __restrict__ U3,
    float* __restrict__ rhs_t)
{
    int bn = blockIdx.x;
    int f = threadIdx.x;
    __shared__ float sl[64][25];
    const u16x8* hp = (const u16x8*)(h + (size_t)bn * cFT + f * cT);
    float u = U3[f];
    #pragma unroll
    for (int v8 = 0; v8 < 3; v8++) {
        u16x8 hv = hp[v8];
        #pragma unroll
        for (int e = 0; e < 8; e++)
            sl[f][v8 * 8 + e] = u * bf2f(hv[e]);
    }
    __syncthreads();
    if (f < cT) {
        float s = 0.f;
        #pragma unroll
        for (int c = 0; c < 64; c++) s += sl[c][f];
        rhs_t[(size_t)bn * cT + f] = s;
    }
}

// ---------------------------------------------------------------------------
__global__ __launch_bounds__(576) void k_E(
    const float* __restrict__ lhs_t, const float* __restrict__ rhs_t,
    const float* __restrict__ be, const float* __restrict__ Ve,
    float* __restrict__ E)
{
    int b = blockIdx.x;
    int tid = threadIdx.x;
    int i = tid / 24, j = tid % 24;
    __shared__ float ps[24][25];
    __shared__ float er[24][25];
    __shared__ float mrow[24], srow[24];
    const float* lp = lhs_t + ((size_t)b * cT + i) * cN;
    const float* rp = rhs_t + (size_t)b * cN * cT;
    float s = 0.f;
    for (int n = 0; n < cN; n++) s += lp[n] * rp[n * cT + j];
    s += be[i * cT + j];
    ps[i][j] = 1.f / (1.f + expf(-s));
    __syncthreads();
    float e = 0.f;
    #pragma unroll
    for (int ss = 0; ss < cT; ss++) e += Ve[i * cT + ss] * ps[ss][j];
    er[i][j] = e;
    __syncthreads();
    if (j == 0) {
        float m = -1e30f;
        for (int r = 0; r < cT; r++) m = fmaxf(m, er[i][r]);
        float sm = 0.f;
        for (int r = 0; r < cT; r++) sm += expf(er[i][r] - m);
        mrow[i] = m;
        srow[i] = sm;
    }
    __syncthreads();
    E[(size_t)b * cT * cT + i * cT + j] = expf(er[i][j] - mrow[i]) / srow[i];
}

// ---------------------------------------------------------------------------
// temporal mixing from bf16 h, emits hT[b,n,t,f] bf16
__global__ __launch_bounds__(256) void k_tmix_t(
    const unsigned short* __restrict__ h, const float* __restrict__ E,
    unsigned short* __restrict__ hT)
{
    int bn = blockIdx.x;
    int b = bn >> 9;
    int tid = threadIdx.x;
    __shared__ float hs[64][25];
    __shared__ float Es[24][24];
    __shared__ float outs[24][65];
    const u16x8* hp = (const u16x8*)(h + (size_t)bn * cFT);
    // 1536 bf16 = 192 vec8; 24 = 3*8 so each vec8 stays in one f-row
    for (int i = tid; i < 192; i += 256) {
        u16x8 v = hp[i];
        int f = i / 3, t0 = (i % 3) * 8;
        #pragma unroll
        for (int e = 0; e < 8; e++) hs[f][t0 + e] = bf2f(v[e]);
    }
    for (int i = tid; i < 576; i += 256)
        Es[i / 24][i % 24] = E[(size_t)b * 576 + i];
    __syncthreads();
    int f = tid & 63, g = tid >> 6;
    #pragma unroll
    for (int j = 0; j < 6; j++) {
        int so = g * 6 + j;
        float s = 0.f;
        #pragma unroll
        for (int t = 0; t < cT; t++) s += hs[f][t] * Es[t][so];
        outs[so][f] = s;
    }
    __syncthreads();
    unsigned short* op = hT + (size_t)bn * cFT;
    for (int i = tid; i < cFT; i += 256)
        op[i] = f2bf(outs[i >> 6][i & 63]);
}

// ---------------------------------------------------------------------------
// MFMA conv(1,3) + bias + residual(x) + LayerNorm over F. float4 stores.
// (round-12 version: separate LDS arrays, NO unions)
__global__ __launch_bounds__(256) void k_convmfma(
    const unsigned short* __restrict__ hT,   // [b,n,t,f] bf16
    const float* __restrict__ x,             // [b,n,c,t] f32
    const unsigned short* __restrict__ W2g,  // [f][192] bf16, k=(d*64+fi)
    const float* __restrict__ cb,
    const float* __restrict__ lnw, const float* __restrict__ lnb,
    float* __restrict__ out)                 // [b,n,f,t] f32
{
    __shared__ unsigned short Hs[8][26][72];
    __shared__ unsigned short Ws[64][200];
    int tid = threadIdx.x;
    int blk = blockIdx.x;
    int b = blk >> 6;
    int n0 = (blk & 63) * 8;
    const unsigned short* hp = hT + ((size_t)b * cN + n0) * cFT;

    #pragma unroll
    for (int it = 0; it < 6; it++) {
        int v = tid + it * 256;
        int s = v / 192;
        int r = v % 192;
        int t = r >> 3, f0 = (r & 7) * 8;
        u16x8 val = *(const u16x8*)(hp + (size_t)s * cFT + t * 64 + f0);
        *(u16x8*)&Hs[s][1 + t][f0] = val;
    }
    if (tid < 144) {
        int s = tid / 18, rm = tid % 18;
        int side = rm / 9, c8 = (rm % 9) * 8;
        u16x8 z = {};
        *(u16x8*)&Hs[s][side * 25][c8] = z;
    }
    #pragma unroll
    for (int it = 0; it < 48; it++) {
        int i = tid + it * 256;
        Ws[i / 192][i % 192] = W2g[i];
    }
    __syncthreads();

    int lane = tid & 63, w = tid >> 6;
    int fr = lane & 15, kgrp = lane >> 4;
    f32x4 acc[3][4] = {};

    int sA[3], tA[3];
    #pragma unroll
    for (int mi = 0; mi < 3; mi++) {
        int row = (w * 3 + mi) * 16 + fr;
        sA[mi] = row / 24; tA[mi] = row % 24;
    }
    #pragma unroll
    for (int ks = 0; ks < 6; ks++) {
        int d = ks >> 1;
        int fi0 = (ks & 1) * 32 + kgrp * 8;
        s16x8 bf[4];
        #pragma unroll
        for (int j = 0; j < 4; j++)
            bf[j] = *(const s16x8*)&Ws[j * 16 + fr][ks * 32 + kgrp * 8];
        #pragma unroll
        for (int mi = 0; mi < 3; mi++) {
            s16x8 af = *(const s16x8*)&Hs[sA[mi]][tA[mi] + d][fi0];
            #pragma unroll
            for (int j = 0; j < 4; j++)
                acc[mi][j] = __builtin_amdgcn_mfma_f32_16x16x32_bf16(
                    af, bf[j], acc[mi][j], 0, 0, 0);
        }
    }

    float lnw_v[4], lnb_v[4], cb_v[4];
    #pragma unroll
    for (int j = 0; j < 4; j++) {
        int f = j * 16 + fr;
        lnw_v[j] = lnw[f]; lnb_v[j] = lnb[f]; cb_v[j] = cb[f];
    }
    #pragma unroll
    for (int mi = 0; mi < 3; mi++) {
        int rowbase = (w * 3 + mi) * 16 + kgrp * 4;
        int sB = rowbase / 24, tb = rowbase % 24;
        size_t slab = ((size_t)b * cN + n0 + sB) * 64;
        float outv[4][4];   // [j][r]
        #pragma unroll
        for (int r = 0; r < 4; r++) {
            int t = tb + r;
            float v[4], s1 = 0.f, s2 = 0.f;
            #pragma unroll
            for (int j = 0; j < 4; j++) {
                float xres = x[(slab + j * 16 + fr) * 24 + t];
                v[j] = acc[mi][j][r] + cb_v[j] + xres;
                s1 += v[j];
                s2 += v[j] * v[j];
            }
            #pragma unroll
            for (int off = 1; off < 16; off <<= 1) {
                s1 += __shfl_xor(s1, off, 64);
                s2 += __shfl_xor(s2, off, 64);
            }
            float mean = s1 * (1.f / 64.f);
            float var = s2 * (1.f / 64.f) - mean * mean;
            float rstd = rsqrtf(var + 1e-5f);
            #pragma unroll
            for (int j = 0; j < 4; j++)
                outv[j][r] = (v[j] - mean) * rstd * lnw_v[j] + lnb_v[j];
        }
        #pragma unroll
        for (int j = 0; j < 4; j++) {
            float4 o = make_float4(outv[j][0], outv[j][1], outv[j][2], outv[j][3]);
            *(float4*)&out[(slab + j * 16 + fr) * 24 + tb] = o;
        }
    }
}

// ---------------------------------------------------------------------------
extern "C" void kernel_launch(void* const* d_in, const int* in_sizes, int n_in,
                              void* d_out, int out_size, void* d_ws, size_t ws_size,
                              hipStream_t stream)
{
    const float* x     = (const float*)d_in[0];
    const float* cheb  = (const float*)d_in[1];
    const float* W1    = (const float*)d_in[2];
    const float* W2    = (const float*)d_in[3];
    const float* W3    = (const float*)d_in[4];
    const float* bs    = (const float*)d_in[5];
    const float* Vs    = (const float*)d_in[6];
    const float* U1    = (const float*)d_in[7];
    const float* U2    = (const float*)d_in[8];
    const float* U3    = (const float*)d_in[9];
    const float* be    = (const float*)d_in[10];
    const float* Ve    = (const float*)d_in[11];
    const float* Theta = (const float*)d_in[12];
    const float* cw    = (const float*)d_in[13];
    const float* cbp   = (const float*)d_in[14];
    const float* lnw   = (const float*)d_in[15];
    const float* lnb   = (const float*)d_in[16];
    float* out = (float*)d_out;
    float* ws  = (float*)d_ws;

    // workspace layout: round-12 PASSING layout (peak ws 138.5 MB).
    // bf16 h (hbf) lives in d_out's first 50 MB; fully dead before k_convmfma
    // overwrites d_out (stream-ordered). NO LDS unions anywhere (r9-11 lesson).
    unsigned short* Vs_bf   = (unsigned short*)(ws);              // 131072 f32
    unsigned short* cheb_bf = (unsigned short*)(ws + 131072);     // 393216 f32
    float*  lhs  = ws + 524288;     // 393216 (also lhs_t)
    float*  rhs  = ws + 917504;     // 393216 (also rhs_t)
    float*  part = ws + 1310720;    // 786432
    unsigned short* ThT = (unsigned short*)(ws + 1310720);        // overlays part (dead before part's first write)
    float*  Ebuf = ws + 2097152;    // 18432
    unsigned short* W2g = (unsigned short*)(ws + 2115584);        // 12288 u16 = 6144 f32
    unsigned short* St  = (unsigned short*)(ws + 2124800);        // 8388608 u16
    unsigned short* Wk  = (unsigned short*)(ws + 6319104);        // 12582912 u16
    unsigned short* XTt = (unsigned short*)(ws + 12610560);       // 37748736 u16 -> ends f32 31484928
    unsigned short* Pt  = (unsigned short*)(ws + 12610560);       // overlay (dead before XTt)
    float*          S0  = ws + 22047744;                          // 8388608 f32 (dead before XTt)
    unsigned short* xT2 = (unsigned short*)(ws + 31484928);       // 6291456 u16 (per half)
    unsigned short* hbf = (unsigned short*)out;                   // 25165824 u16 = 50 MB of d_out
    unsigned short* hT  = XTt;                                    // reuse after GEMM loop

    const long long NN2 = (long long)cN * cN;        // 262144
    const long long NFT = (long long)cN * cFT;       // 786432
    const long long segW = 16LL * NN2;               // Wk k-segment (u16 elems)
    const long long segX = 16LL * 1536 * 512;        // XTt k-segment

    k_convert<<<1024, 256, 0, stream>>>(Vs, Vs_bf, 262144);
    k_convert<<<3072, 256, 0, stream>>>(cheb, cheb_bf, 786432);
    k_wprep<<<48, 256, 0, stream>>>(cw, W2g);
    k_thprep<<<48, 256, 0, stream>>>(Theta, ThT);

    // spatial attention
    k_spatial_lr<<<cB * cN, 64, 0, stream>>>(x, W1, W2, W3, lhs, rhs);
    k_product_t<<<dim3(32, 32, cB), dim3(16, 16), 0, stream>>>(lhs, rhs, bs, Pt);
    k_mfma_gemm<0><<<dim3(4, 4, cB), 256, 0, stream>>>(
        Vs_bf, 512, 0LL, 0LL, Pt, 512, NN2, 0LL, S0, 512, NN2, 512, 0, 0);
    k_softmax512<<<cB * cN, 256, 0, stream>>>(S0);
    k_transpose_S<<<dim3(8, 8, cB), 256, 0, stream>>>(S0, St);

    // Cheb conv, batch-halved with fused-K final GEMM -> h (bf16+relu) in d_out
    for (int half = 0; half < 2; half++) {
        k_xtrans_half<<<16 * 512, 64, 0, stream>>>(x, half, xT2);
        k_xtheta_mfma<<<dim3(4, 24, 16), 256, 0, stream>>>(xT2, ThT, XTt, segX);
        for (int k = 0; k < cK; k++) {
            k_mfma_gemm<1><<<dim3(4, 4, 16), 256, 0, stream>>>(
                cheb_bf + (size_t)k * NN2, 512, 0LL, 0LL,
                St + (size_t)half * 16 * NN2, 512, NN2, 0LL,
                Wk + (size_t)k * segW, 512, NN2, 512, 0, 0);
        }
        k_mfma_gemm<1><<<dim3(12, 4, 16), 256, 0, stream>>>(
            Wk, 512, NN2, segW, XTt, 512, 786432LL, segX,
            hbf + (size_t)half * 16 * NFT, 1536, NFT, 1536, 0, 1);
    }

    // temporal attention (reads h = hbf bf16; ThT dead from here)
    k_hU1_part<<<dim3(cB, 16), 256, 0, stream>>>(hbf, U1, part);
    k_rhs_t<<<cB * cN, 64, 0, stream>>>(hbf, U3, rhs);
    k_lhs_t<<<dim3(cB, 4), 256, 0, stream>>>(part, U2, lhs);
    k_E<<<cB, 576, 0, stream>>>(lhs, rhs, be, Ve, Ebuf);

    // temporal mixing -> hT (bf16, [t,f]; hbf dead after), then conv + LN -> out
    k_tmix_t<<<cB * cN, 256, 0, stream>>>(hbf, Ebuf, hT);
    k_convmfma<<<2048, 256, 0, stream>>>(hT, x, W2g, cbp, lnw, lnb, out);
}

// Round 15
// 543.434 us; speedup vs baseline: 2.3392x; 1.1095x over previous
//
#include <hip/hip_runtime.h>

// Problem constants
constexpr int cB = 32, cN = 512, cC = 64, cT = 24, cK = 3, cF = 64;
constexpr int cCT = cC * cT;   // 1536
constexpr int cFT = cF * cT;   // 1536

typedef __attribute__((ext_vector_type(8))) short s16x8;            // MFMA bf16 frag
typedef __attribute__((ext_vector_type(8))) unsigned short u16x8;   // 16B load/store
typedef __attribute__((ext_vector_type(4))) float f32x4;            // MFMA acc

__device__ inline unsigned short f2bf(float f) {
    union { float f; unsigned int u; } v; v.f = f;
    unsigned int r = v.u + 0x7FFFu + ((v.u >> 16) & 1u);
    return (unsigned short)(r >> 16);
}
__device__ inline float bf2f(unsigned short u) {
    union { unsigned int i; float f; } v; v.i = ((unsigned int)u) << 16;
    return v.f;
}

// ---------------------------------------------------------------------------
__global__ __launch_bounds__(64) void k_spatial_lr(
    const float* __restrict__ x, const float* __restrict__ W1,
    const float* __restrict__ W2, const float* __restrict__ W3,
    float* __restrict__ lhs, float* __restrict__ rhs)
{
    int bn = blockIdx.x;
    int tid = threadIdx.x;
    __shared__ float xs[64][25];
    __shared__ float a_sh[64];
    const float* xp = x + (size_t)bn * cCT;
    for (int i = tid; i < cCT; i += 64) xs[i / cT][i % cT] = xp[i];
    __syncthreads();
    float s = 0.f;
    #pragma unroll
    for (int t = 0; t < cT; t++) s += xs[tid][t] * W1[t];
    a_sh[tid] = s;
    __syncthreads();
    if (tid < cT) {
        float l = 0.f, r = 0.f;
        for (int c = 0; c < cC; c++) {
            l += a_sh[c] * W2[c * cT + tid];
            r += xs[c][tid] * W3[c];
        }
        lhs[(size_t)bn * cT + tid] = l;
        rhs[(size_t)bn * cT + tid] = r;
    }
}

// ---------------------------------------------------------------------------
// Pt[b,n,m] = bf16(sigmoid(sum_t lhs[b,m,t]*rhs[b,n,t] + bs[m,n]))  (transposed)
__global__ __launch_bounds__(256) void k_product_t(
    const float* __restrict__ lhs, const float* __restrict__ rhs,
    const float* __restrict__ bs, unsigned short* __restrict__ Pt)
{
    int b = blockIdx.z;
    int m0 = blockIdx.y * 16, n0 = blockIdx.x * 16;
    int tx = threadIdx.x, ty = threadIdx.y;
    int tid = ty * 16 + tx;
    __shared__ float L[16][25], R[16][25], bss[16][17];
    for (int i = tid; i < 16 * cT; i += 256) {
        int r = i / cT, c = i % cT;
        L[r][c] = lhs[((size_t)b * cN + m0 + r) * cT + c];
        R[r][c] = rhs[((size_t)b * cN + n0 + r) * cT + c];
    }
    bss[tid >> 4][tid & 15] = bs[(size_t)(m0 + (tid >> 4)) * cN + n0 + (tid & 15)];
    __syncthreads();
    float s = 0.f;
    #pragma unroll
    for (int t = 0; t < cT; t++) s += L[tx][t] * R[ty][t];
    s += bss[tx][ty];
    float sig = 1.f / (1.f + expf(-s));
    Pt[((size_t)b * cN + n0 + ty) * cN + m0 + tx] = f2bf(sig);
}

// ---------------------------------------------------------------------------
// Batched bf16 MFMA GEMM, 128x128 tile, BK=32, 4 waves, 16x16x32 MFMA.
// Segmented K (512 per segment). Pass segA=segB=0 for K<=512.
// CM==0: C f32 (doAcc/doRelu). CM==1: C bf16 (doRelu honored).
template<int CM>
__global__ __launch_bounds__(256) void k_mfma_gemm(
    const unsigned short* __restrict__ A, int lda, long long aB, long long segA,
    const unsigned short* __restrict__ Bt, int ldb, long long bB, long long segB,
    void* __restrict__ Cv, int ldc, long long cBs,
    int K, int doAcc, int doRelu)
{
    __shared__ unsigned short As[128][40];
    __shared__ unsigned short Bs[128][40];
    int tid = threadIdx.x;
    int bn = blockIdx.x * 128;
    int bm = blockIdx.y * 128;
    int z  = blockIdx.z;
    const unsigned short* Ap = A  + (size_t)z * aB;
    const unsigned short* Bp = Bt + (size_t)z * bB;

    int lane = tid & 63, w = tid >> 6;
    int wm = (w >> 1) * 64, wn = (w & 1) * 64;
    int fr = lane & 15, kg = (lane >> 4) * 8;

    f32x4 acc[4][4] = {};

    int c0 = tid, c1 = tid + 256;
    int r0 = c0 >> 2, g0 = (c0 & 3) * 8;
    int r1 = c1 >> 2, g1 = (c1 & 3) * 8;

    for (int k0 = 0; k0 < K; k0 += 32) {
        int seg = k0 >> 9, off = k0 & 511;
        const unsigned short* Aseg = Ap + (size_t)seg * segA;
        const unsigned short* Bseg = Bp + (size_t)seg * segB;
        u16x8 a0 = *(const u16x8*)(Aseg + (size_t)(bm + r0) * lda + off + g0);
        u16x8 a1 = *(const u16x8*)(Aseg + (size_t)(bm + r1) * lda + off + g1);
        u16x8 b0 = *(const u16x8*)(Bseg + (size_t)(bn + r0) * ldb + off + g0);
        u16x8 b1 = *(const u16x8*)(Bseg + (size_t)(bn + r1) * ldb + off + g1);
        __syncthreads();
        *(u16x8*)&As[r0][g0] = a0;
        *(u16x8*)&As[r1][g1] = a1;
        *(u16x8*)&Bs[r0][g0] = b0;
        *(u16x8*)&Bs[r1][g1] = b1;
        __syncthreads();
        s16x8 af[4], bf[4];
        #pragma unroll
        for (int i = 0; i < 4; i++)
            af[i] = *(const s16x8*)&As[wm + i * 16 + fr][kg];
        #pragma unroll
        for (int j = 0; j < 4; j++)
            bf[j] = *(const s16x8*)&Bs[wn + j * 16 + fr][kg];
        #pragma unroll
        for (int i = 0; i < 4; i++)
            #pragma unroll
            for (int j = 0; j < 4; j++)
                acc[i][j] = __builtin_amdgcn_mfma_f32_16x16x32_bf16(
                    af[i], bf[j], acc[i][j], 0, 0, 0);
    }
    int rb = (lane >> 4) * 4;
    if (CM == 0) {
        float* Cp = (float*)Cv + (size_t)z * cBs;
        #pragma unroll
        for (int i = 0; i < 4; i++) {
            int row = bm + wm + i * 16 + rb;
            #pragma unroll
            for (int j = 0; j < 4; j++) {
                int col = bn + wn + j * 16 + fr;
                #pragma unroll
                for (int r = 0; r < 4; r++) {
                    size_t idx = (size_t)(row + r) * ldc + col;
                    float v = acc[i][j][r];
                    if (doAcc) v += Cp[idx];
                    if (doRelu) v = fmaxf(v, 0.f);
                    Cp[idx] = v;
                }
            }
        }
    } else {
        unsigned short* Cp = (unsigned short*)Cv + (size_t)z * cBs;
        #pragma unroll
        for (int i = 0; i < 4; i++) {
            int row = bm + wm + i * 16 + rb;
            #pragma unroll
            for (int j = 0; j < 4; j++) {
                int col = bn + wn + j * 16 + fr;
                #pragma unroll
                for (int r = 0; r < 4; r++) {
                    float v = acc[i][j][r];
                    if (doRelu) v = fmaxf(v, 0.f);
                    Cp[(size_t)(row + r) * ldc + col] = f2bf(v);
                }
            }
        }
    }
}

// ---------------------------------------------------------------------------
__global__ __launch_bounds__(256) void k_softmax512(float* __restrict__ S)
{
    int row = blockIdx.x;
    int tid = threadIdx.x;
    float* p = S + (size_t)row * cN;
    float v0 = p[tid], v1 = p[tid + 256];
    __shared__ float red[256];
    red[tid] = fmaxf(v0, v1);
    __syncthreads();
    for (int off = 128; off > 0; off >>= 1) {
        if (tid < off) red[tid] = fmaxf(red[tid], red[tid + off]);
        __syncthreads();
    }
    float mx = red[0];
    __syncthreads();
    float e0 = expf(v0 - mx), e1 = expf(v1 - mx);
    red[tid] = e0 + e1;
    __syncthreads();
    for (int off = 128; off > 0; off >>= 1) {
        if (tid < off) red[tid] += red[tid + off];
        __syncthreads();
    }
    float inv = 1.f / red[0];
    p[tid] = e0 * inv;
    p[tid + 256] = e1 * inv;
}

// ---------------------------------------------------------------------------
__global__ __launch_bounds__(256) void k_transpose_S(
    const float* __restrict__ S0, unsigned short* __restrict__ St)
{
    int b = blockIdx.z;
    int q0 = blockIdx.y * 64, n0 = blockIdx.x * 64;
    __shared__ float t[64][68];
    int tid = threadIdx.x;
    int r = tid >> 2, grp = (tid & 3) * 16;
    const float* ip = S0 + ((size_t)b * cN + q0 + r) * cN + n0 + grp;
    #pragma unroll
    for (int i = 0; i < 16; i += 4)
        *(float4*)&t[r][grp + i] = *(const float4*)(ip + i);
    __syncthreads();
    int nr = tid & 63, qg = (tid >> 6) * 16;
    unsigned short* op = St + ((size_t)b * cN + n0 + nr) * cN + q0 + qg;
    u16x8 v0, v1;
    #pragma unroll
    for (int i = 0; i < 8; i++) {
        v0[i] = f2bf(t[qg + i][nr]);
        v1[i] = f2bf(t[qg + 8 + i][nr]);
    }
    *(u16x8*)op = v0;
    *(u16x8*)(op + 8) = v1;
}

// ---------------------------------------------------------------------------
// xT2[z][t][n][c] = bf16(x[half*16+z][n][c][t])   (one pass per half)
__global__ __launch_bounds__(64) void k_xtrans_half(
    const float* __restrict__ x, int half, unsigned short* __restrict__ xT2)
{
    int idx = blockIdx.x;            // z*512 + n
    int z = idx >> 9, n = idx & 511;
    int b = half * 16 + z;
    int tid = threadIdx.x;
    __shared__ float xs[64][25];
    const float* xp = x + (size_t)(b * (size_t)cN + n) * cCT;
    for (int i = tid; i < cCT; i += 64) xs[i / cT][i % cT] = xp[i];
    __syncthreads();
    unsigned short* op = xT2 + (size_t)z * 786432 + (size_t)n * 64;
    for (int i = tid; i < cCT; i += 64) {
        int t = i >> 6, c = i & 63;
        op[(size_t)t * 32768 + c] = f2bf(xs[c][t]);
    }
}

// ---------------------------------------------------------------------------
// XT via MFMA, direct write to XTt[k][z][f*24+t][n].
__global__ __launch_bounds__(256) void k_xtheta_mfma(
    const unsigned short* __restrict__ xT2,   // [z][t][n][c]
    const unsigned short* __restrict__ ThT,   // [k][f][c]
    unsigned short* __restrict__ XTt,         // [k][z][f*24+t][n]
    long long segX)
{
    __shared__ unsigned short As[128][72];
    __shared__ unsigned short Ths[64][72];
    __shared__ unsigned short Cs[64][136];
    int tid = threadIdx.x;
    int n0 = blockIdx.x * 128;
    int t  = blockIdx.y;
    int z  = blockIdx.z;

    const unsigned short* ap = xT2 + (size_t)z * 786432 + (size_t)t * 32768 + n0 * 64;
    #pragma unroll
    for (int it = 0; it < 4; it++) {
        int v = tid + it * 256;
        int row = v >> 3, c8 = (v & 7) * 8;
        *(u16x8*)&As[row][c8] = *(const u16x8*)(ap + row * 64 + c8);
    }

    int lane = tid & 63, w = tid >> 6;
    int fr = lane & 15, kg = (lane >> 4) * 8;
    int rb = (lane >> 4) * 4;

    for (int k = 0; k < cK; k++) {
        __syncthreads();   // prev Cs/Ths reads + (k=0) A-stage done
        #pragma unroll
        for (int it = 0; it < 2; it++) {
            int vi = tid + it * 256;         // 0..511
            int row = vi >> 3, c8 = (vi & 7) * 8;
            *(u16x8*)&Ths[row][c8] =
                *(const u16x8*)(ThT + (size_t)k * 4096 + row * 64 + c8);
        }
        __syncthreads();
        f32x4 acc[2][4] = {};
        #pragma unroll
        for (int ks = 0; ks < 2; ks++) {
            s16x8 af[2], bf[4];
            #pragma unroll
            for (int i = 0; i < 2; i++)
                af[i] = *(const s16x8*)&As[w * 32 + i * 16 + fr][ks * 32 + kg];
            #pragma unroll
            for (int j = 0; j < 4; j++)
                bf[j] = *(const s16x8*)&Ths[j * 16 + fr][ks * 32 + kg];
            #pragma unroll
            for (int i = 0; i < 2; i++)
                #pragma unroll
                for (int j = 0; j < 4; j++)
                    acc[i][j] = __builtin_amdgcn_mfma_f32_16x16x32_bf16(
                        af[i], bf[j], acc[i][j], 0, 0, 0);
        }
        #pragma unroll
        for (int i = 0; i < 2; i++) {
            int rowb = w * 32 + i * 16 + rb;
            #pragma unroll
            for (int j = 0; j < 4; j++) {
                int f = j * 16 + fr;
                #pragma unroll
                for (int r = 0; r < 4; r++)
                    Cs[f][rowb + r] = f2bf(acc[i][j][r]);
            }
        }
        __syncthreads();
        unsigned short* op = XTt + (size_t)k * segX + (size_t)z * 786432 + n0;
        #pragma unroll
        for (int it = 0; it < 4; it++) {
            int v = tid + it * 256;
            int f = v >> 4, n8 = (v & 15) * 8;
            *(u16x8*)(op + (size_t)(f * 24 + t) * 512 + n8) = *(const u16x8*)&Cs[f][n8];
        }
    }
}

// ---------------------------------------------------------------------------
__global__ void k_convert(const float* __restrict__ a,
                          unsigned short* __restrict__ o, int n)
{
    int i = blockIdx.x * 256 + threadIdx.x;
    if (i < n) o[i] = f2bf(a[i]);
}

// ---------------------------------------------------------------------------
// W2g[f][d*64+fi] = bf16(conv_w[f][fi][0][d])
__global__ void k_wprep(const float* __restrict__ cw,
                        unsigned short* __restrict__ W2g)
{
    int i = blockIdx.x * 256 + threadIdx.x;
    if (i < 64 * 192) {
        int f = i / 192, k = i % 192;
        int d = k >> 6, fi = k & 63;
        W2g[i] = f2bf(cw[f * 192 + fi * 3 + d]);
    }
}

// ---------------------------------------------------------------------------
// ThT[k][f][c] = bf16(Theta[k][c][f])
__global__ void k_thprep(const float* __restrict__ Theta,
                         unsigned short* __restrict__ ThT)
{
    int i = blockIdx.x * 256 + threadIdx.x;
    if (i < cK * 64 * 64) {
        int k = i >> 12, r = i & 4095;
        int f = r >> 6, c = r & 63;
        ThT[i] = f2bf(Theta[k * 4096 + c * 64 + f]);
    }
}

// ---------------------------------------------------------------------------
// partial hU1 from bf16 h
__global__ __launch_bounds__(256) void k_hU1_part(
    const unsigned short* __restrict__ h, const float* __restrict__ U1,
    float* __restrict__ part)
{
    int b = blockIdx.x, nc = blockIdx.y;
    int tid = threadIdx.x;
    int f = tid & 63, q = tid >> 6;
    float acc[24];
    #pragma unroll
    for (int t = 0; t < 24; t++) acc[t] = 0.f;
    for (int n = nc * 32 + q; n < nc * 32 + 32; n += 4) {
        float u = U1[n];
        const u16x8* hp = (const u16x8*)(h + (((size_t)b * cN + n) * cF + f) * cT);
        #pragma unroll
        for (int v8 = 0; v8 < 3; v8++) {
            u16x8 hv = hp[v8];
            #pragma unroll
            for (int e = 0; e < 8; e++)
                acc[v8 * 8 + e] += u * bf2f(hv[e]);
        }
    }
    __shared__ float ps[4][64][25];
    #pragma unroll
    for (int t = 0; t < 24; t++) ps[q][f][t] = acc[t];
    __syncthreads();
    for (int i = tid; i < cFT; i += 256) {
        int f2 = i / cT, t2 = i % cT;
        float s = ps[0][f2][t2] + ps[1][f2][t2] + ps[2][f2][t2] + ps[3][f2][t2];
        part[(((size_t)b * 16 + nc) * cF + f2) * cT + t2] = s;
    }
}

// ---------------------------------------------------------------------------
__global__ __launch_bounds__(256) void k_lhs_t(
    const float* __restrict__ part, const float* __restrict__ U2,
    float* __restrict__ lhs_t)
{
    int b = blockIdx.x, ch = blockIdx.y;
    int tid = threadIdx.x;
    __shared__ float hu[1536];
    for (int i = tid; i < 1536; i += 256) {
        float s = 0.f;
        for (int nc = 0; nc < 16; nc++)
            s += part[((size_t)b * 16 + nc) * 1536 + i];
        hu[i] = s;
    }
    __syncthreads();
    int nn0 = ch * 128;
    for (int i = tid; i < cT * 128; i += 256) {
        int t = i / 128, nn = nn0 + (i % 128);
        float s = 0.f;
        #pragma unroll
        for (int f = 0; f < 64; f++) s += hu[f * cT + t] * U2[(size_t)f * cN + nn];
        lhs_t[((size_t)b * cT + t) * cN + nn] = s;
    }
}

// ---------------------------------------------------------------------------
// rhs_t from bf16 h
__global__ __launch_bounds__(64) void k_rhs_t(
    const unsigned short* __restrict__ h, const float* __restrict__ U3,
    float* __restrict__ rhs_t)
{
    int bn = blockIdx.x;
    int f = threadIdx.x;
    __shared__ float sl[64][25];
    const u16x8* hp = (const u16x8*)(h + (size_t)bn * cFT + f * cT);
    float u = U3[f];
    #pragma unroll
    for (int v8 = 0; v8 < 3; v8++) {
        u16x8 hv = hp[v8];
        #pragma unroll
        for (int e = 0; e < 8; e++)
            sl[f][v8 * 8 + e] = u * bf2f(hv[e]);
    }
    __syncthreads();
    if (f < cT) {
        float s = 0.f;
        #pragma unroll
        for (int c = 0; c < 64; c++) s += sl[c][f];
        rhs_t[(size_t)bn * cT + f] = s;
    }
}

// ---------------------------------------------------------------------------
__global__ __launch_bounds__(576) void k_E(
    const float* __restrict__ lhs_t, const float* __restrict__ rhs_t,
    const float* __restrict__ be, const float* __restrict__ Ve,
    float* __restrict__ E)
{
    int b = blockIdx.x;
    int tid = threadIdx.x;
    int i = tid / 24, j = tid % 24;
    __shared__ float ps[24][25];
    __shared__ float er[24][25];
    __shared__ float mrow[24], srow[24];
    const float* lp = lhs_t + ((size_t)b * cT + i) * cN;
    const float* rp = rhs_t + (size_t)b * cN * cT;
    float s = 0.f;
    for (int n = 0; n < cN; n++) s += lp[n] * rp[n * cT + j];
    s += be[i * cT + j];
    ps[i][j] = 1.f / (1.f + expf(-s));
    __syncthreads();
    float e = 0.f;
    #pragma unroll
    for (int ss = 0; ss < cT; ss++) e += Ve[i * cT + ss] * ps[ss][j];
    er[i][j] = e;
    __syncthreads();
    if (j == 0) {
        float m = -1e30f;
        for (int r = 0; r < cT; r++) m = fmaxf(m, er[i][r]);
        float sm = 0.f;
        for (int r = 0; r < cT; r++) sm += expf(er[i][r] - m);
        mrow[i] = m;
        srow[i] = sm;
    }
    __syncthreads();
    E[(size_t)b * cT * cT + i * cT + j] = expf(er[i][j] - mrow[i]) / srow[i];
}

// ---------------------------------------------------------------------------
// MFMA temporal mixing: hT[b,n,so,f] = sum_t h[b,n,f,t] * E[b][t][so].
// Per block: 8 slabs; A = E^T (M=so, K=t zero-padded to 32), B = h (k-contig).
// Fragment conventions identical to k_mfma_gemm (verified kernel).
__global__ __launch_bounds__(256) void k_tmix_mfma(
    const unsigned short* __restrict__ h,   // hbf [b,n,f,t] bf16
    const float* __restrict__ E,            // [b][24][24]
    unsigned short* __restrict__ hT)        // [b,n,t,f] bf16
{
    __shared__ float Es[24][25];
    __shared__ unsigned short bounce[8][24][64];
    int tid = threadIdx.x;
    int blk = blockIdx.x;            // 2048
    int b = blk >> 6;
    int n0 = (blk & 63) * 8;
    for (int i = tid; i < 576; i += 256)
        Es[i / 24][i % 24] = E[(size_t)b * 576 + i];
    __syncthreads();

    int lane = tid & 63, w = tid >> 6;
    int fr = lane & 15, g = lane >> 4;

    // A-frags from E^T: element e -> A[so][t], so = m*16+fr, t = g*8+e.
    s16x8 afr[2];
    #pragma unroll
    for (int m = 0; m < 2; m++) {
        int so = m * 16 + fr;
        u16x8 a = {};
        if (so < 24 && g < 3) {
            #pragma unroll
            for (int e = 0; e < 8; e++)
                a[e] = f2bf(Es[g * 8 + e][so]);
        }
        afr[m] = *(s16x8*)&a;
    }

    f32x4 zero = {};
    #pragma unroll
    for (int ss = 0; ss < 2; ss++) {
        int s = w * 2 + ss;
        const unsigned short* hp = h + ((size_t)b * cN + n0 + s) * cFT;
        #pragma unroll
        for (int jj = 0; jj < 4; jj++) {
            u16x8 bfrag = {};
            if (g < 3)   // B[t][f] frag: f = jj*16+fr, t = g*8+e (contig in h)
                bfrag = *(const u16x8*)(hp + (jj * 16 + fr) * 24 + g * 8);
            s16x8 bf = *(s16x8*)&bfrag;
            #pragma unroll
            for (int m = 0; m < 2; m++) {
                f32x4 c = __builtin_amdgcn_mfma_f32_16x16x32_bf16(
                    afr[m], bf, zero, 0, 0, 0);
                #pragma unroll
                for (int r = 0; r < 4; r++) {
                    int so = m * 16 + g * 4 + r;
                    if (so < 24)
                        bounce[s][so][jj * 16 + fr] = f2bf(c[r]);
                }
            }
        }
    }
    __syncthreads();
    // coalesced drain: bounce [8][24][64] == hT slab-major layout
    unsigned short* op = hT + ((size_t)b * cN + n0) * cFT;
    #pragma unroll
    for (int it = 0; it < 6; it++) {
        int i = tid + it * 256;   // 1536 vec8
        *(u16x8*)(op + i * 8) = *(const u16x8*)&bounce[0][0][i * 8];
    }
}

// ---------------------------------------------------------------------------
// MFMA conv(1,3) + bias + residual(x) + LayerNorm over F. float4 stores.
__global__ __launch_bounds__(256) void k_convmfma(
    const unsigned short* __restrict__ hT,   // [b,n,t,f] bf16
    const float* __restrict__ x,             // [b,n,c,t] f32
    const unsigned short* __restrict__ W2g,  // [f][192] bf16, k=(d*64+fi)
    const float* __restrict__ cb,
    const float* __restrict__ lnw, const float* __restrict__ lnb,
    float* __restrict__ out)                 // [b,n,f,t] f32
{
    __shared__ unsigned short Hs[8][26][72];
    __shared__ unsigned short Ws[64][200];
    int tid = threadIdx.x;
    int blk = blockIdx.x;
    int b = blk >> 6;
    int n0 = (blk & 63) * 8;
    const unsigned short* hp = hT + ((size_t)b * cN + n0) * cFT;

    #pragma unroll
    for (int it = 0; it < 6; it++) {
        int v = tid + it * 256;
        int s = v / 192;
        int r = v % 192;
        int t = r >> 3, f0 = (r & 7) * 8;
        u16x8 val = *(const u16x8*)(hp + (size_t)s * cFT + t * 64 + f0);
        *(u16x8*)&Hs[s][1 + t][f0] = val;
    }
    if (tid < 144) {
        int s = tid / 18, rm = tid % 18;
        int side = rm / 9, c8 = (rm % 9) * 8;
        u16x8 z = {};
        *(u16x8*)&Hs[s][side * 25][c8] = z;
    }
    #pragma unroll
    for (int it = 0; it < 48; it++) {
        int i = tid + it * 256;
        Ws[i / 192][i % 192] = W2g[i];
    }
    __syncthreads();

    int lane = tid & 63, w = tid >> 6;
    int fr = lane & 15, kgrp = lane >> 4;
    f32x4 acc[3][4] = {};

    int sA[3], tA[3];
    #pragma unroll
    for (int mi = 0; mi < 3; mi++) {
        int row = (w * 3 + mi) * 16 + fr;
        sA[mi] = row / 24; tA[mi] = row % 24;
    }
    #pragma unroll
    for (int ks = 0; ks < 6; ks++) {
        int d = ks >> 1;
        int fi0 = (ks & 1) * 32 + kgrp * 8;
        s16x8 bf[4];
        #pragma unroll
        for (int j = 0; j < 4; j++)
            bf[j] = *(const s16x8*)&Ws[j * 16 + fr][ks * 32 + kgrp * 8];
        #pragma unroll
        for (int mi = 0; mi < 3; mi++) {
            s16x8 af = *(const s16x8*)&Hs[sA[mi]][tA[mi] + d][fi0];
            #pragma unroll
            for (int j = 0; j < 4; j++)
                acc[mi][j] = __builtin_amdgcn_mfma_f32_16x16x32_bf16(
                    af, bf[j], acc[mi][j], 0, 0, 0);
        }
    }

    float lnw_v[4], lnb_v[4], cb_v[4];
    #pragma unroll
    for (int j = 0; j < 4; j++) {
        int f = j * 16 + fr;
        lnw_v[j] = lnw[f]; lnb_v[j] = lnb[f]; cb_v[j] = cb[f];
    }
    #pragma unroll
    for (int mi = 0; mi < 3; mi++) {
        int rowbase = (w * 3 + mi) * 16 + kgrp * 4;
        int sB = rowbase / 24, tb = rowbase % 24;
        size_t slab = ((size_t)b * cN + n0 + sB) * 64;
        float outv[4][4];   // [j][r]
        #pragma unroll
        for (int r = 0; r < 4; r++) {
            int t = tb + r;
            float v[4], s1 = 0.f, s2 = 0.f;
            #pragma unroll
            for (int j = 0; j < 4; j++) {
                float xres = x[(slab + j * 16 + fr) * 24 + t];
                v[j] = acc[mi][j][r] + cb_v[j] + xres;
                s1 += v[j];
                s2 += v[j] * v[j];
            }
            #pragma unroll
            for (int off = 1; off < 16; off <<= 1) {
                s1 += __shfl_xor(s1, off, 64);
                s2 += __shfl_xor(s2, off, 64);
            }
            float mean = s1 * (1.f / 64.f);
            float var = s2 * (1.f / 64.f) - mean * mean;
            float rstd = rsqrtf(var + 1e-5f);
            #pragma unroll
            for (int j = 0; j < 4; j++)
                outv[j][r] = (v[j] - mean) * rstd * lnw_v[j] + lnb_v[j];
        }
        #pragma unroll
        for (int j = 0; j < 4; j++) {
            float4 o = make_float4(outv[j][0], outv[j][1], outv[j][2], outv[j][3]);
            *(float4*)&out[(slab + j * 16 + fr) * 24 + tb] = o;
        }
    }
}

// ---------------------------------------------------------------------------
extern "C" void kernel_launch(void* const* d_in, const int* in_sizes, int n_in,
                              void* d_out, int out_size, void* d_ws, size_t ws_size,
                              hipStream_t stream)
{
    const float* x     = (const float*)d_in[0];
    const float* cheb  = (const float*)d_in[1];
    const float* W1    = (const float*)d_in[2];
    const float* W2    = (const float*)d_in[3];
    const float* W3    = (const float*)d_in[4];
    const float* bs    = (const float*)d_in[5];
    const float* Vs    = (const float*)d_in[6];
    const float* U1    = (const float*)d_in[7];
    const float* U2    = (const float*)d_in[8];
    const float* U3    = (const float*)d_in[9];
    const float* be    = (const float*)d_in[10];
    const float* Ve    = (const float*)d_in[11];
    const float* Theta = (const float*)d_in[12];
    const float* cw    = (const float*)d_in[13];
    const float* cbp   = (const float*)d_in[14];
    const float* lnw   = (const float*)d_in[15];
    const float* lnb   = (const float*)d_in[16];
    float* out = (float*)d_out;
    float* ws  = (float*)d_ws;

    // workspace layout: round-14 PASSING layout (peak ws 138.5 MB).
    // bf16 h (hbf) in d_out's first 50 MB; dead before k_convmfma writes d_out.
    unsigned short* Vs_bf   = (unsigned short*)(ws);              // 131072 f32
    unsigned short* cheb_bf = (unsigned short*)(ws + 131072);     // 393216 f32
    float*  lhs  = ws + 524288;     // 393216 (also lhs_t)
    float*  rhs  = ws + 917504;     // 393216 (also rhs_t)
    float*  part = ws + 1310720;    // 786432
    unsigned short* ThT = (unsigned short*)(ws + 1310720);        // overlays part (dead before part's first write)
    float*  Ebuf = ws + 2097152;    // 18432
    unsigned short* W2g = (unsigned short*)(ws + 2115584);        // 12288 u16 = 6144 f32
    unsigned short* St  = (unsigned short*)(ws + 2124800);        // 8388608 u16
    unsigned short* Wk  = (unsigned short*)(ws + 6319104);        // 12582912 u16
    unsigned short* XTt = (unsigned short*)(ws + 12610560);       // 37748736 u16 -> ends f32 31484928
    unsigned short* Pt  = (unsigned short*)(ws + 12610560);       // overlay (dead before XTt)
    float*          S0  = ws + 22047744;                          // 8388608 f32 (dead before XTt)
    unsigned short* xT2 = (unsigned short*)(ws + 31484928);       // 6291456 u16 (per half)
    unsigned short* hbf = (unsigned short*)out;                   // 25165824 u16 = 50 MB of d_out
    unsigned short* hT  = XTt;                                    // reuse after GEMM loop

    const long long NN2 = (long long)cN * cN;        // 262144
    const long long NFT = (long long)cN * cFT;       // 786432
    const long long segW = 16LL * NN2;               // Wk k-segment (u16 elems)
    const long long segX = 16LL * 1536 * 512;        // XTt k-segment

    k_convert<<<1024, 256, 0, stream>>>(Vs, Vs_bf, 262144);
    k_convert<<<3072, 256, 0, stream>>>(cheb, cheb_bf, 786432);
    k_wprep<<<48, 256, 0, stream>>>(cw, W2g);
    k_thprep<<<48, 256, 0, stream>>>(Theta, ThT);

    // spatial attention
    k_spatial_lr<<<cB * cN, 64, 0, stream>>>(x, W1, W2, W3, lhs, rhs);
    k_product_t<<<dim3(32, 32, cB), dim3(16, 16), 0, stream>>>(lhs, rhs, bs, Pt);
    k_mfma_gemm<0><<<dim3(4, 4, cB), 256, 0, stream>>>(
        Vs_bf, 512, 0LL, 0LL, Pt, 512, NN2, 0LL, S0, 512, NN2, 512, 0, 0);
    k_softmax512<<<cB * cN, 256, 0, stream>>>(S0);
    k_transpose_S<<<dim3(8, 8, cB), 256, 0, stream>>>(S0, St);

    // Cheb conv, batch-halved with fused-K final GEMM -> h (bf16+relu) in d_out
    for (int half = 0; half < 2; half++) {
        k_xtrans_half<<<16 * 512, 64, 0, stream>>>(x, half, xT2);
        k_xtheta_mfma<<<dim3(4, 24, 16), 256, 0, stream>>>(xT2, ThT, XTt, segX);
        for (int k = 0; k < cK; k++) {
            k_mfma_gemm<1><<<dim3(4, 4, 16), 256, 0, stream>>>(
                cheb_bf + (size_t)k * NN2, 512, 0LL, 0LL,
                St + (size_t)half * 16 * NN2, 512, NN2, 0LL,
                Wk + (size_t)k * segW, 512, NN2, 512, 0, 0);
        }
        k_mfma_gemm<1><<<dim3(12, 4, 16), 256, 0, stream>>>(
            Wk, 512, NN2, segW, XTt, 512, 786432LL, segX,
            hbf + (size_t)half * 16 * NFT, 1536, NFT, 1536, 0, 1);
    }

    // temporal attention (reads h = hbf bf16; ThT dead from here)
    k_hU1_part<<<dim3(cB, 16), 256, 0, stream>>>(hbf, U1, part);
    k_rhs_t<<<cB * cN, 64, 0, stream>>>(hbf, U3, rhs);
    k_lhs_t<<<dim3(cB, 4), 256, 0, stream>>>(part, U2, lhs);
    k_E<<<cB, 576, 0, stream>>>(lhs, rhs, be, Ve, Ebuf);

    // temporal mixing via MFMA -> hT (bf16, [t,f]; hbf dead after), conv+LN -> out
    k_tmix_mfma<<<2048, 256, 0, stream>>>(hbf, Ebuf, hT);
    k_convmfma<<<2048, 256, 0, stream>>>(hT, x, W2g, cbp, lnw, lnb, out);
}

// Round 16
// 532.940 us; speedup vs baseline: 2.3852x; 1.0197x over previous
//
#include <hip/hip_runtime.h>

// Problem constants
constexpr int cB = 32, cN = 512, cC = 64, cT = 24, cK = 3, cF = 64;
constexpr int cCT = cC * cT;   // 1536
constexpr int cFT = cF * cT;   // 1536

typedef __attribute__((ext_vector_type(8))) short s16x8;            // MFMA bf16 frag
typedef __attribute__((ext_vector_type(8))) unsigned short u16x8;   // 16B load/store
typedef __attribute__((ext_vector_type(4))) float f32x4;            // MFMA acc

__device__ inline unsigned short f2bf(float f) {
    union { float f; unsigned int u; } v; v.f = f;
    unsigned int r = v.u + 0x7FFFu + ((v.u >> 16) & 1u);
    return (unsigned short)(r >> 16);
}
__device__ inline float bf2f(unsigned short u) {
    union { unsigned int i; float f; } v; v.i = ((unsigned int)u) << 16;
    return v.f;
}

// ---------------------------------------------------------------------------
__global__ __launch_bounds__(64) void k_spatial_lr(
    const float* __restrict__ x, const float* __restrict__ W1,
    const float* __restrict__ W2, const float* __restrict__ W3,
    float* __restrict__ lhs, float* __restrict__ rhs)
{
    int bn = blockIdx.x;
    int tid = threadIdx.x;
    __shared__ float xs[64][25];
    __shared__ float a_sh[64];
    const float* xp = x + (size_t)bn * cCT;
    for (int i = tid; i < cCT; i += 64) xs[i / cT][i % cT] = xp[i];
    __syncthreads();
    float s = 0.f;
    #pragma unroll
    for (int t = 0; t < cT; t++) s += xs[tid][t] * W1[t];
    a_sh[tid] = s;
    __syncthreads();
    if (tid < cT) {
        float l = 0.f, r = 0.f;
        for (int c = 0; c < cC; c++) {
            l += a_sh[c] * W2[c * cT + tid];
            r += xs[c][tid] * W3[c];
        }
        lhs[(size_t)bn * cT + tid] = l;
        rhs[(size_t)bn * cT + tid] = r;
    }
}

// ---------------------------------------------------------------------------
// Pt[b,n,m] = bf16(sigmoid(sum_t lhs[b,m,t]*rhs[b,n,t] + bs[m,n]))  (transposed)
__global__ __launch_bounds__(256) void k_product_t(
    const float* __restrict__ lhs, const float* __restrict__ rhs,
    const float* __restrict__ bs, unsigned short* __restrict__ Pt)
{
    int b = blockIdx.z;
    int m0 = blockIdx.y * 16, n0 = blockIdx.x * 16;
    int tx = threadIdx.x, ty = threadIdx.y;
    int tid = ty * 16 + tx;
    __shared__ float L[16][25], R[16][25], bss[16][17];
    for (int i = tid; i < 16 * cT; i += 256) {
        int r = i / cT, c = i % cT;
        L[r][c] = lhs[((size_t)b * cN + m0 + r) * cT + c];
        R[r][c] = rhs[((size_t)b * cN + n0 + r) * cT + c];
    }
    bss[tid >> 4][tid & 15] = bs[(size_t)(m0 + (tid >> 4)) * cN + n0 + (tid & 15)];
    __syncthreads();
    float s = 0.f;
    #pragma unroll
    for (int t = 0; t < cT; t++) s += L[tx][t] * R[ty][t];
    s += bss[tx][ty];
    float sig = 1.f / (1.f + expf(-s));
    Pt[((size_t)b * cN + n0 + ty) * cN + m0 + tx] = f2bf(sig);
}

// ---------------------------------------------------------------------------
// Batched bf16 MFMA GEMM, 128x128 tile, BK=32, 4 waves, 16x16x32 MFMA.
// 1-D grid with XCD-chunked swizzle: each XCD gets a contiguous z-major range
// so L2 keeps the active A/B slices resident across tile re-reads.
// Segmented K (512 per segment). Pass segA=segB=0 for K<=512.
// CM==0: C f32 (doAcc/doRelu). CM==1: C bf16 (doRelu honored).
template<int CM>
__global__ __launch_bounds__(256) void k_mfma_gemm(
    const unsigned short* __restrict__ A, int lda, long long aB, long long segA,
    const unsigned short* __restrict__ Bt, int ldb, long long bB, long long segB,
    void* __restrict__ Cv, int ldc, long long cBs,
    int K, int doAcc, int doRelu, int nx, int ny)
{
    __shared__ unsigned short As[128][40];
    __shared__ unsigned short Bs[128][40];
    int tid = threadIdx.x;
    // XCD-chunked swizzle (grid size divisible by 8)
    int nb = gridDim.x;
    int bid = blockIdx.x;
    int xcd = bid & 7, loc = bid >> 3;
    int nid = xcd * (nb >> 3) + loc;
    int z   = nid / (nx * ny);
    int rem = nid % (nx * ny);
    int bm  = (rem / nx) * 128;
    int bn  = (rem % nx) * 128;

    const unsigned short* Ap = A  + (size_t)z * aB;
    const unsigned short* Bp = Bt + (size_t)z * bB;

    int lane = tid & 63, w = tid >> 6;
    int wm = (w >> 1) * 64, wn = (w & 1) * 64;
    int fr = lane & 15, kg = (lane >> 4) * 8;

    f32x4 acc[4][4] = {};

    int c0 = tid, c1 = tid + 256;
    int r0 = c0 >> 2, g0 = (c0 & 3) * 8;
    int r1 = c1 >> 2, g1 = (c1 & 3) * 8;

    for (int k0 = 0; k0 < K; k0 += 32) {
        int seg = k0 >> 9, off = k0 & 511;
        const unsigned short* Aseg = Ap + (size_t)seg * segA;
        const unsigned short* Bseg = Bp + (size_t)seg * segB;
        u16x8 a0 = *(const u16x8*)(Aseg + (size_t)(bm + r0) * lda + off + g0);
        u16x8 a1 = *(const u16x8*)(Aseg + (size_t)(bm + r1) * lda + off + g1);
        u16x8 b0 = *(const u16x8*)(Bseg + (size_t)(bn + r0) * ldb + off + g0);
        u16x8 b1 = *(const u16x8*)(Bseg + (size_t)(bn + r1) * ldb + off + g1);
        __syncthreads();
        *(u16x8*)&As[r0][g0] = a0;
        *(u16x8*)&As[r1][g1] = a1;
        *(u16x8*)&Bs[r0][g0] = b0;
        *(u16x8*)&Bs[r1][g1] = b1;
        __syncthreads();
        s16x8 af[4], bf[4];
        #pragma unroll
        for (int i = 0; i < 4; i++)
            af[i] = *(const s16x8*)&As[wm + i * 16 + fr][kg];
        #pragma unroll
        for (int j = 0; j < 4; j++)
            bf[j] = *(const s16x8*)&Bs[wn + j * 16 + fr][kg];
        #pragma unroll
        for (int i = 0; i < 4; i++)
            #pragma unroll
            for (int j = 0; j < 4; j++)
                acc[i][j] = __builtin_amdgcn_mfma_f32_16x16x32_bf16(
                    af[i], bf[j], acc[i][j], 0, 0, 0);
    }
    int rb = (lane >> 4) * 4;
    if (CM == 0) {
        float* Cp = (float*)Cv + (size_t)z * cBs;
        #pragma unroll
        for (int i = 0; i < 4; i++) {
            int row = bm + wm + i * 16 + rb;
            #pragma unroll
            for (int j = 0; j < 4; j++) {
                int col = bn + wn + j * 16 + fr;
                #pragma unroll
                for (int r = 0; r < 4; r++) {
                    size_t idx = (size_t)(row + r) * ldc + col;
                    float v = acc[i][j][r];
                    if (doAcc) v += Cp[idx];
                    if (doRelu) v = fmaxf(v, 0.f);
                    Cp[idx] = v;
                }
            }
        }
    } else {
        unsigned short* Cp = (unsigned short*)Cv + (size_t)z * cBs;
        #pragma unroll
        for (int i = 0; i < 4; i++) {
            int row = bm + wm + i * 16 + rb;
            #pragma unroll
            for (int j = 0; j < 4; j++) {
                int col = bn + wn + j * 16 + fr;
                #pragma unroll
                for (int r = 0; r < 4; r++) {
                    float v = acc[i][j][r];
                    if (doRelu) v = fmaxf(v, 0.f);
                    Cp[(size_t)(row + r) * ldc + col] = f2bf(v);
                }
            }
        }
    }
}

// ---------------------------------------------------------------------------
__global__ __launch_bounds__(256) void k_softmax512(float* __restrict__ S)
{
    int row = blockIdx.x;
    int tid = threadIdx.x;
    float* p = S + (size_t)row * cN;
    float v0 = p[tid], v1 = p[tid + 256];
    __shared__ float red[256];
    red[tid] = fmaxf(v0, v1);
    __syncthreads();
    for (int off = 128; off > 0; off >>= 1) {
        if (tid < off) red[tid] = fmaxf(red[tid], red[tid + off]);
        __syncthreads();
    }
    float mx = red[0];
    __syncthreads();
    float e0 = expf(v0 - mx), e1 = expf(v1 - mx);
    red[tid] = e0 + e1;
    __syncthreads();
    for (int off = 128; off > 0; off >>= 1) {
        if (tid < off) red[tid] += red[tid + off];
        __syncthreads();
    }
    float inv = 1.f / red[0];
    p[tid] = e0 * inv;
    p[tid + 256] = e1 * inv;
}

// ---------------------------------------------------------------------------
__global__ __launch_bounds__(256) void k_transpose_S(
    const float* __restrict__ S0, unsigned short* __restrict__ St)
{
    int b = blockIdx.z;
    int q0 = blockIdx.y * 64, n0 = blockIdx.x * 64;
    __shared__ float t[64][68];
    int tid = threadIdx.x;
    int r = tid >> 2, grp = (tid & 3) * 16;
    const float* ip = S0 + ((size_t)b * cN + q0 + r) * cN + n0 + grp;
    #pragma unroll
    for (int i = 0; i < 16; i += 4)
        *(float4*)&t[r][grp + i] = *(const float4*)(ip + i);
    __syncthreads();
    int nr = tid & 63, qg = (tid >> 6) * 16;
    unsigned short* op = St + ((size_t)b * cN + n0 + nr) * cN + q0 + qg;
    u16x8 v0, v1;
    #pragma unroll
    for (int i = 0; i < 8; i++) {
        v0[i] = f2bf(t[qg + i][nr]);
        v1[i] = f2bf(t[qg + 8 + i][nr]);
    }
    *(u16x8*)op = v0;
    *(u16x8*)(op + 8) = v1;
}

// ---------------------------------------------------------------------------
// xT2[z][t][n][c] = bf16(x[half*16+z][n][c][t])   (one pass per half)
__global__ __launch_bounds__(64) void k_xtrans_half(
    const float* __restrict__ x, int half, unsigned short* __restrict__ xT2)
{
    int idx = blockIdx.x;            // z*512 + n
    int z = idx >> 9, n = idx & 511;
    int b = half * 16 + z;
    int tid = threadIdx.x;
    __shared__ float xs[64][25];
    const float* xp = x + (size_t)(b * (size_t)cN + n) * cCT;
    for (int i = tid; i < cCT; i += 64) xs[i / cT][i % cT] = xp[i];
    __syncthreads();
    unsigned short* op = xT2 + (size_t)z * 786432 + (size_t)n * 64;
    for (int i = tid; i < cCT; i += 64) {
        int t = i >> 6, c = i & 63;
        op[(size_t)t * 32768 + c] = f2bf(xs[c][t]);
    }
}

// ---------------------------------------------------------------------------
// XT via MFMA, direct write to XTt[k][z][f*24+t][n].
__global__ __launch_bounds__(256) void k_xtheta_mfma(
    const unsigned short* __restrict__ xT2,   // [z][t][n][c]
    const unsigned short* __restrict__ ThT,   // [k][f][c]
    unsigned short* __restrict__ XTt,         // [k][z][f*24+t][n]
    long long segX)
{
    __shared__ unsigned short As[128][72];
    __shared__ unsigned short Ths[64][72];
    __shared__ unsigned short Cs[64][136];
    int tid = threadIdx.x;
    int n0 = blockIdx.x * 128;
    int t  = blockIdx.y;
    int z  = blockIdx.z;

    const unsigned short* ap = xT2 + (size_t)z * 786432 + (size_t)t * 32768 + n0 * 64;
    #pragma unroll
    for (int it = 0; it < 4; it++) {
        int v = tid + it * 256;
        int row = v >> 3, c8 = (v & 7) * 8;
        *(u16x8*)&As[row][c8] = *(const u16x8*)(ap + row * 64 + c8);
    }

    int lane = tid & 63, w = tid >> 6;
    int fr = lane & 15, kg = (lane >> 4) * 8;
    int rb = (lane >> 4) * 4;

    for (int k = 0; k < cK; k++) {
        __syncthreads();   // prev Cs/Ths reads + (k=0) A-stage done
        #pragma unroll
        for (int it = 0; it < 2; it++) {
            int vi = tid + it * 256;         // 0..511
            int row = vi >> 3, c8 = (vi & 7) * 8;
            *(u16x8*)&Ths[row][c8] =
                *(const u16x8*)(ThT + (size_t)k * 4096 + row * 64 + c8);
        }
        __syncthreads();
        f32x4 acc[2][4] = {};
        #pragma unroll
        for (int ks = 0; ks < 2; ks++) {
            s16x8 af[2], bf[4];
            #pragma unroll
            for (int i = 0; i < 2; i++)
                af[i] = *(const s16x8*)&As[w * 32 + i * 16 + fr][ks * 32 + kg];
            #pragma unroll
            for (int j = 0; j < 4; j++)
                bf[j] = *(const s16x8*)&Ths[j * 16 + fr][ks * 32 + kg];
            #pragma unroll
            for (int i = 0; i < 2; i++)
                #pragma unroll
                for (int j = 0; j < 4; j++)
                    acc[i][j] = __builtin_amdgcn_mfma_f32_16x16x32_bf16(
                        af[i], bf[j], acc[i][j], 0, 0, 0);
        }
        #pragma unroll
        for (int i = 0; i < 2; i++) {
            int rowb = w * 32 + i * 16 + rb;
            #pragma unroll
            for (int j = 0; j < 4; j++) {
                int f = j * 16 + fr;
                #pragma unroll
                for (int r = 0; r < 4; r++)
                    Cs[f][rowb + r] = f2bf(acc[i][j][r]);
            }
        }
        __syncthreads();
        unsigned short* op = XTt + (size_t)k * segX + (size_t)z * 786432 + n0;
        #pragma unroll
        for (int it = 0; it < 4; it++) {
            int v = tid + it * 256;
            int f = v >> 4, n8 = (v & 15) * 8;
            *(u16x8*)(op + (size_t)(f * 24 + t) * 512 + n8) = *(const u16x8*)&Cs[f][n8];
        }
    }
}

// ---------------------------------------------------------------------------
__global__ void k_convert(const float* __restrict__ a,
                          unsigned short* __restrict__ o, int n)
{
    int i = blockIdx.x * 256 + threadIdx.x;
    if (i < n) o[i] = f2bf(a[i]);
}

// ---------------------------------------------------------------------------
// W2g[f][d*64+fi] = bf16(conv_w[f][fi][0][d])
__global__ void k_wprep(const float* __restrict__ cw,
                        unsigned short* __restrict__ W2g)
{
    int i = blockIdx.x * 256 + threadIdx.x;
    if (i < 64 * 192) {
        int f = i / 192, k = i % 192;
        int d = k >> 6, fi = k & 63;
        W2g[i] = f2bf(cw[f * 192 + fi * 3 + d]);
    }
}

// ---------------------------------------------------------------------------
// ThT[k][f][c] = bf16(Theta[k][c][f])
__global__ void k_thprep(const float* __restrict__ Theta,
                         unsigned short* __restrict__ ThT)
{
    int i = blockIdx.x * 256 + threadIdx.x;
    if (i < cK * 64 * 64) {
        int k = i >> 12, r = i & 4095;
        int f = r >> 6, c = r & 63;
        ThT[i] = f2bf(Theta[k * 4096 + c * 64 + f]);
    }
}

// ---------------------------------------------------------------------------
// partial hU1 from bf16 h
__global__ __launch_bounds__(256) void k_hU1_part(
    const unsigned short* __restrict__ h, const float* __restrict__ U1,
    float* __restrict__ part)
{
    int b = blockIdx.x, nc = blockIdx.y;
    int tid = threadIdx.x;
    int f = tid & 63, q = tid >> 6;
    float acc[24];
    #pragma unroll
    for (int t = 0; t < 24; t++) acc[t] = 0.f;
    for (int n = nc * 32 + q; n < nc * 32 + 32; n += 4) {
        float u = U1[n];
        const u16x8* hp = (const u16x8*)(h + (((size_t)b * cN + n) * cF + f) * cT);
        #pragma unroll
        for (int v8 = 0; v8 < 3; v8++) {
            u16x8 hv = hp[v8];
            #pragma unroll
            for (int e = 0; e < 8; e++)
                acc[v8 * 8 + e] += u * bf2f(hv[e]);
        }
    }
    __shared__ float ps[4][64][25];
    #pragma unroll
    for (int t = 0; t < 24; t++) ps[q][f][t] = acc[t];
    __syncthreads();
    for (int i = tid; i < cFT; i += 256) {
        int f2 = i / cT, t2 = i % cT;
        float s = ps[0][f2][t2] + ps[1][f2][t2] + ps[2][f2][t2] + ps[3][f2][t2];
        part[(((size_t)b * 16 + nc) * cF + f2) * cT + t2] = s;
    }
}

// ---------------------------------------------------------------------------
__global__ __launch_bounds__(256) void k_lhs_t(
    const float* __restrict__ part, const float* __restrict__ U2,
    float* __restrict__ lhs_t)
{
    int b = blockIdx.x, ch = blockIdx.y;
    int tid = threadIdx.x;
    __shared__ float hu[1536];
    for (int i = tid; i < 1536; i += 256) {
        float s = 0.f;
        for (int nc = 0; nc < 16; nc++)
            s += part[((size_t)b * 16 + nc) * 1536 + i];
        hu[i] = s;
    }
    __syncthreads();
    int nn0 = ch * 128;
    for (int i = tid; i < cT * 128; i += 256) {
        int t = i / 128, nn = nn0 + (i % 128);
        float s = 0.f;
        #pragma unroll
        for (int f = 0; f < 64; f++) s += hu[f * cT + t] * U2[(size_t)f * cN + nn];
        lhs_t[((size_t)b * cT + t) * cN + nn] = s;
    }
}

// ---------------------------------------------------------------------------
// rhs_t from bf16 h
__global__ __launch_bounds__(64) void k_rhs_t(
    const unsigned short* __restrict__ h, const float* __restrict__ U3,
    float* __restrict__ rhs_t)
{
    int bn = blockIdx.x;
    int f = threadIdx.x;
    __shared__ float sl[64][25];
    const u16x8* hp = (const u16x8*)(h + (size_t)bn * cFT + f * cT);
    float u = U3[f];
    #pragma unroll
    for (int v8 = 0; v8 < 3; v8++) {
        u16x8 hv = hp[v8];
        #pragma unroll
        for (int e = 0; e < 8; e++)
            sl[f][v8 * 8 + e] = u * bf2f(hv[e]);
    }
    __syncthreads();
    if (f < cT) {
        float s = 0.f;
        #pragma unroll
        for (int c = 0; c < 64; c++) s += sl[c][f];
        rhs_t[(size_t)bn * cT + f] = s;
    }
}

// ---------------------------------------------------------------------------
__global__ __launch_bounds__(576) void k_E(
    const float* __restrict__ lhs_t, const float* __restrict__ rhs_t,
    const float* __restrict__ be, const float* __restrict__ Ve,
    float* __restrict__ E)
{
    int b = blockIdx.x;
    int tid = threadIdx.x;
    int i = tid / 24, j = tid % 24;
    __shared__ float ps[24][25];
    __shared__ float er[24][25];
    __shared__ float mrow[24], srow[24];
    const float* lp = lhs_t + ((size_t)b * cT + i) * cN;
    const float* rp = rhs_t + (size_t)b * cN * cT;
    float s = 0.f;
    for (int n = 0; n < cN; n++) s += lp[n] * rp[n * cT + j];
    s += be[i * cT + j];
    ps[i][j] = 1.f / (1.f + expf(-s));
    __syncthreads();
    float e = 0.f;
    #pragma unroll
    for (int ss = 0; ss < cT; ss++) e += Ve[i * cT + ss] * ps[ss][j];
    er[i][j] = e;
    __syncthreads();
    if (j == 0) {
        float m = -1e30f;
        for (int r = 0; r < cT; r++) m = fmaxf(m, er[i][r]);
        float sm = 0.f;
        for (int r = 0; r < cT; r++) sm += expf(er[i][r] - m);
        mrow[i] = m;
        srow[i] = sm;
    }
    __syncthreads();
    E[(size_t)b * cT * cT + i * cT + j] = expf(er[i][j] - mrow[i]) / srow[i];
}

// ---------------------------------------------------------------------------
// MFMA temporal mixing: hT[b,n,so,f] = sum_t h[b,n,f,t] * E[b][t][so].
__global__ __launch_bounds__(256) void k_tmix_mfma(
    const unsigned short* __restrict__ h,   // hbf [b,n,f,t] bf16
    const float* __restrict__ E,            // [b][24][24]
    unsigned short* __restrict__ hT)        // [b,n,t,f] bf16
{
    __shared__ float Es[24][25];
    __shared__ unsigned short bounce[8][24][64];
    int tid = threadIdx.x;
    int blk = blockIdx.x;            // 2048
    int b = blk >> 6;
    int n0 = (blk & 63) * 8;
    for (int i = tid; i < 576; i += 256)
        Es[i / 24][i % 24] = E[(size_t)b * 576 + i];
    __syncthreads();

    int lane = tid & 63, w = tid >> 6;
    int fr = lane & 15, g = lane >> 4;

    s16x8 afr[2];
    #pragma unroll
    for (int m = 0; m < 2; m++) {
        int so = m * 16 + fr;
        u16x8 a = {};
        if (so < 24 && g < 3) {
            #pragma unroll
            for (int e = 0; e < 8; e++)
                a[e] = f2bf(Es[g * 8 + e][so]);
        }
        afr[m] = *(s16x8*)&a;
    }

    f32x4 zero = {};
    #pragma unroll
    for (int ss = 0; ss < 2; ss++) {
        int s = w * 2 + ss;
        const unsigned short* hp = h + ((size_t)b * cN + n0 + s) * cFT;
        #pragma unroll
        for (int jj = 0; jj < 4; jj++) {
            u16x8 bfrag = {};
            if (g < 3)
                bfrag = *(const u16x8*)(hp + (jj * 16 + fr) * 24 + g * 8);
            s16x8 bf = *(s16x8*)&bfrag;
            #pragma unroll
            for (int m = 0; m < 2; m++) {
                f32x4 c = __builtin_amdgcn_mfma_f32_16x16x32_bf16(
                    afr[m], bf, zero, 0, 0, 0);
                #pragma unroll
                for (int r = 0; r < 4; r++) {
                    int so = m * 16 + g * 4 + r;
                    if (so < 24)
                        bounce[s][so][jj * 16 + fr] = f2bf(c[r]);
                }
            }
        }
    }
    __syncthreads();
    unsigned short* op = hT + ((size_t)b * cN + n0) * cFT;
    #pragma unroll
    for (int it = 0; it < 6; it++) {
        int i = tid + it * 256;
        *(u16x8*)(op + i * 8) = *(const u16x8*)&bounce[0][0][i * 8];
    }
}

// ---------------------------------------------------------------------------
// MFMA conv(1,3) + bias + residual(x) + LayerNorm over F. float4 stores.
__global__ __launch_bounds__(256) void k_convmfma(
    const unsigned short* __restrict__ hT,   // [b,n,t,f] bf16
    const float* __restrict__ x,             // [b,n,c,t] f32
    const unsigned short* __restrict__ W2g,  // [f][192] bf16, k=(d*64+fi)
    const float* __restrict__ cb,
    const float* __restrict__ lnw, const float* __restrict__ lnb,
    float* __restrict__ out)                 // [b,n,f,t] f32
{
    __shared__ unsigned short Hs[8][26][72];
    __shared__ unsigned short Ws[64][200];
    int tid = threadIdx.x;
    int blk = blockIdx.x;
    int b = blk >> 6;
    int n0 = (blk & 63) * 8;
    const unsigned short* hp = hT + ((size_t)b * cN + n0) * cFT;

    #pragma unroll
    for (int it = 0; it < 6; it++) {
        int v = tid + it * 256;
        int s = v / 192;
        int r = v % 192;
        int t = r >> 3, f0 = (r & 7) * 8;
        u16x8 val = *(const u16x8*)(hp + (size_t)s * cFT + t * 64 + f0);
        *(u16x8*)&Hs[s][1 + t][f0] = val;
    }
    if (tid < 144) {
        int s = tid / 18, rm = tid % 18;
        int side = rm / 9, c8 = (rm % 9) * 8;
        u16x8 z = {};
        *(u16x8*)&Hs[s][side * 25][c8] = z;
    }
    #pragma unroll
    for (int it = 0; it < 48; it++) {
        int i = tid + it * 256;
        Ws[i / 192][i % 192] = W2g[i];
    }
    __syncthreads();

    int lane = tid & 63, w = tid >> 6;
    int fr = lane & 15, kgrp = lane >> 4;
    f32x4 acc[3][4] = {};

    int sA[3], tA[3];
    #pragma unroll
    for (int mi = 0; mi < 3; mi++) {
        int row = (w * 3 + mi) * 16 + fr;
        sA[mi] = row / 24; tA[mi] = row % 24;
    }
    #pragma unroll
    for (int ks = 0; ks < 6; ks++) {
        int d = ks >> 1;
        int fi0 = (ks & 1) * 32 + kgrp * 8;
        s16x8 bf[4];
        #pragma unroll
        for (int j = 0; j < 4; j++)
            bf[j] = *(const s16x8*)&Ws[j * 16 + fr][ks * 32 + kgrp * 8];
        #pragma unroll
        for (int mi = 0; mi < 3; mi++) {
            s16x8 af = *(const s16x8*)&Hs[sA[mi]][tA[mi] + d][fi0];
            #pragma unroll
            for (int j = 0; j < 4; j++)
                acc[mi][j] = __builtin_amdgcn_mfma_f32_16x16x32_bf16(
                    af, bf[j], acc[mi][j], 0, 0, 0);
        }
    }

    float lnw_v[4], lnb_v[4], cb_v[4];
    #pragma unroll
    for (int j = 0; j < 4; j++) {
        int f = j * 16 + fr;
        lnw_v[j] = lnw[f]; lnb_v[j] = lnb[f]; cb_v[j] = cb[f];
    }
    #pragma unroll
    for (int mi = 0; mi < 3; mi++) {
        int rowbase = (w * 3 + mi) * 16 + kgrp * 4;
        int sB = rowbase / 24, tb = rowbase % 24;
        size_t slab = ((size_t)b * cN + n0 + sB) * 64;
        float outv[4][4];   // [j][r]
        #pragma unroll
        for (int r = 0; r < 4; r++) {
            int t = tb + r;
            float v[4], s1 = 0.f, s2 = 0.f;
            #pragma unroll
            for (int j = 0; j < 4; j++) {
                float xres = x[(slab + j * 16 + fr) * 24 + t];
                v[j] = acc[mi][j][r] + cb_v[j] + xres;
                s1 += v[j];
                s2 += v[j] * v[j];
            }
            #pragma unroll
            for (int off = 1; off < 16; off <<= 1) {
                s1 += __shfl_xor(s1, off, 64);
                s2 += __shfl_xor(s2, off, 64);
            }
            float mean = s1 * (1.f / 64.f);
            float var = s2 * (1.f / 64.f) - mean * mean;
            float rstd = rsqrtf(var + 1e-5f);
            #pragma unroll
            for (int j = 0; j < 4; j++)
                outv[j][r] = (v[j] - mean) * rstd * lnw_v[j] + lnb_v[j];
        }
        #pragma unroll
        for (int j = 0; j < 4; j++) {
            float4 o = make_float4(outv[j][0], outv[j][1], outv[j][2], outv[j][3]);
            *(float4*)&out[(slab + j * 16 + fr) * 24 + tb] = o;
        }
    }
}

// ---------------------------------------------------------------------------
extern "C" void kernel_launch(void* const* d_in, const int* in_sizes, int n_in,
                              void* d_out, int out_size, void* d_ws, size_t ws_size,
                              hipStream_t stream)
{
    const float* x     = (const float*)d_in[0];
    const float* cheb  = (const float*)d_in[1];
    const float* W1    = (const float*)d_in[2];
    const float* W2    = (const float*)d_in[3];
    const float* W3    = (const float*)d_in[4];
    const float* bs    = (const float*)d_in[5];
    const float* Vs    = (const float*)d_in[6];
    const float* U1    = (const float*)d_in[7];
    const float* U2    = (const float*)d_in[8];
    const float* U3    = (const float*)d_in[9];
    const float* be    = (const float*)d_in[10];
    const float* Ve    = (const float*)d_in[11];
    const float* Theta = (const float*)d_in[12];
    const float* cw    = (const float*)d_in[13];
    const float* cbp   = (const float*)d_in[14];
    const float* lnw   = (const float*)d_in[15];
    const float* lnb   = (const float*)d_in[16];
    float* out = (float*)d_out;
    float* ws  = (float*)d_ws;

    // workspace layout: round-14 PASSING layout (peak ws 138.5 MB).
    // bf16 h (hbf) in d_out's first 50 MB; dead before k_convmfma writes d_out.
    unsigned short* Vs_bf   = (unsigned short*)(ws);              // 131072 f32
    unsigned short* cheb_bf = (unsigned short*)(ws + 131072);     // 393216 f32
    float*  lhs  = ws + 524288;     // 393216 (also lhs_t)
    float*  rhs  = ws + 917504;     // 393216 (also rhs_t)
    float*  part = ws + 1310720;    // 786432
    unsigned short* ThT = (unsigned short*)(ws + 1310720);        // overlays part (dead before part's first write)
    float*  Ebuf = ws + 2097152;    // 18432
    unsigned short* W2g = (unsigned short*)(ws + 2115584);        // 12288 u16 = 6144 f32
    unsigned short* St  = (unsigned short*)(ws + 2124800);        // 8388608 u16
    unsigned short* Wk  = (unsigned short*)(ws + 6319104);        // 12582912 u16
    unsigned short* XTt = (unsigned short*)(ws + 12610560);       // 37748736 u16 -> ends f32 31484928
    unsigned short* Pt  = (unsigned short*)(ws + 12610560);       // overlay (dead before XTt)
    float*          S0  = ws + 22047744;                          // 8388608 f32 (dead before XTt)
    unsigned short* xT2 = (unsigned short*)(ws + 31484928);       // 6291456 u16 (per half)
    unsigned short* hbf = (unsigned short*)out;                   // 25165824 u16 = 50 MB of d_out
    unsigned short* hT  = XTt;                                    // reuse after GEMM loop

    const long long NN2 = (long long)cN * cN;        // 262144
    const long long NFT = (long long)cN * cFT;       // 786432
    const long long segW = 16LL * NN2;               // Wk k-segment (u16 elems)
    const long long segX = 16LL * 1536 * 512;        // XTt k-segment

    k_convert<<<1024, 256, 0, stream>>>(Vs, Vs_bf, 262144);
    k_convert<<<3072, 256, 0, stream>>>(cheb, cheb_bf, 786432);
    k_wprep<<<48, 256, 0, stream>>>(cw, W2g);
    k_thprep<<<48, 256, 0, stream>>>(Theta, ThT);

    // spatial attention
    k_spatial_lr<<<cB * cN, 64, 0, stream>>>(x, W1, W2, W3, lhs, rhs);
    k_product_t<<<dim3(32, 32, cB), dim3(16, 16), 0, stream>>>(lhs, rhs, bs, Pt);
    // S0 = Vs @ P: grid 4x4x32 = 512 blocks (1-D swizzled)
    k_mfma_gemm<0><<<512, 256, 0, stream>>>(
        Vs_bf, 512, 0LL, 0LL, Pt, 512, NN2, 0LL, S0, 512, NN2, 512, 0, 0, 4, 4);
    k_softmax512<<<cB * cN, 256, 0, stream>>>(S0);
    k_transpose_S<<<dim3(8, 8, cB), 256, 0, stream>>>(S0, St);

    // Cheb conv, batch-halved with fused-K final GEMM -> h (bf16+relu) in d_out
    for (int half = 0; half < 2; half++) {
        k_xtrans_half<<<16 * 512, 64, 0, stream>>>(x, half, xT2);
        k_xtheta_mfma<<<dim3(4, 24, 16), 256, 0, stream>>>(xT2, ThT, XTt, segX);
        for (int k = 0; k < cK; k++) {
            // W_k = cheb_k @ S: grid 4x4x16 = 256 blocks (1-D swizzled)
            k_mfma_gemm<1><<<256, 256, 0, stream>>>(
                cheb_bf + (size_t)k * NN2, 512, 0LL, 0LL,
                St + (size_t)half * 16 * NN2, 512, NN2, 0LL,
                Wk + (size_t)k * segW, 512, NN2, 512, 0, 0, 4, 4);
        }
        // h_half = relu(sum_k W_k @ XT_k): grid 12x4x16 = 768 blocks (swizzled)
        k_mfma_gemm<1><<<768, 256, 0, stream>>>(
            Wk, 512, NN2, segW, XTt, 512, 786432LL, segX,
            hbf + (size_t)half * 16 * NFT, 1536, NFT, 1536, 0, 1, 12, 4);
    }

    // temporal attention (reads h = hbf bf16; ThT dead from here)
    k_hU1_part<<<dim3(cB, 16), 256, 0, stream>>>(hbf, U1, part);
    k_rhs_t<<<cB * cN, 64, 0, stream>>>(hbf, U3, rhs);
    k_lhs_t<<<dim3(cB, 4), 256, 0, stream>>>(part, U2, lhs);
    k_E<<<cB, 576, 0, stream>>>(lhs, rhs, be, Ve, Ebuf);

    // temporal mixing via MFMA -> hT (bf16, [t,f]; hbf dead after), conv+LN -> out
    k_tmix_mfma<<<2048, 256, 0, stream>>>(hbf, Ebuf, hT);
    k_convmfma<<<2048, 256, 0, stream>>>(hT, x, W2g, cbp, lnw, lnb, out);
}

// Round 17
// 476.892 us; speedup vs baseline: 2.6656x; 1.1175x over previous
//
#include <hip/hip_runtime.h>

// Problem constants
constexpr int cB = 32, cN = 512, cC = 64, cT = 24, cK = 3, cF = 64;
constexpr int cCT = cC * cT;   // 1536
constexpr int cFT = cF * cT;   // 1536

typedef __attribute__((ext_vector_type(8))) short s16x8;            // MFMA bf16 frag
typedef __attribute__((ext_vector_type(8))) unsigned short u16x8;   // 16B load/store
typedef __attribute__((ext_vector_type(4))) float f32x4;            // MFMA acc

__device__ inline unsigned short f2bf(float f) {
    union { float f; unsigned int u; } v; v.f = f;
    unsigned int r = v.u + 0x7FFFu + ((v.u >> 16) & 1u);
    return (unsigned short)(r >> 16);
}
__device__ inline float bf2f(unsigned short u) {
    union { unsigned int i; float f; } v; v.i = ((unsigned int)u) << 16;
    return v.f;
}

// ---------------------------------------------------------------------------
// 4 slabs per 256-thread block; float4 x staging.
__global__ __launch_bounds__(256) void k_spatial_lr(
    const float* __restrict__ x, const float* __restrict__ W1,
    const float* __restrict__ W2, const float* __restrict__ W3,
    float* __restrict__ lhs, float* __restrict__ rhs)
{
    int tid = threadIdx.x;
    int bn0 = blockIdx.x * 4;
    __shared__ float xs[4][64][25];
    __shared__ float a_sh[4][64];
    const float4* xp4 = (const float4*)(x + (size_t)bn0 * cCT);
    // 4 slabs x 384 f4 = 1536 f4
    for (int v = tid; v < 1536; v += 256) {
        int sl = v / 384, i = v % 384;
        float4 f4 = xp4[sl * 384 + i];
        int e = i * 4;
        int c = e / 24, t0 = e % 24;
        xs[sl][c][t0] = f4.x; xs[sl][c][t0 + 1] = f4.y;
        xs[sl][c][t0 + 2] = f4.z; xs[sl][c][t0 + 3] = f4.w;
    }
    __syncthreads();
    int sl = tid >> 6, c = tid & 63;
    float s = 0.f;
    #pragma unroll
    for (int t = 0; t < cT; t++) s += xs[sl][c][t] * W1[t];
    a_sh[sl][c] = s;
    __syncthreads();
    if (c < cT) {
        float l = 0.f, r = 0.f;
        for (int cp = 0; cp < cC; cp++) {
            l += a_sh[sl][cp] * W2[cp * cT + c];
            r += xs[sl][cp][c] * W3[cp];
        }
        lhs[(size_t)(bn0 + sl) * cT + c] = l;
        rhs[(size_t)(bn0 + sl) * cT + c] = r;
    }
}

// ---------------------------------------------------------------------------
// Pt[b,n,m] = bf16(sigmoid(sum_t lhs[b,m,t]*rhs[b,n,t] + bs[m,n]))  (transposed)
__global__ __launch_bounds__(256) void k_product_t(
    const float* __restrict__ lhs, const float* __restrict__ rhs,
    const float* __restrict__ bs, unsigned short* __restrict__ Pt)
{
    int b = blockIdx.z;
    int m0 = blockIdx.y * 16, n0 = blockIdx.x * 16;
    int tx = threadIdx.x, ty = threadIdx.y;
    int tid = ty * 16 + tx;
    __shared__ float L[16][25], R[16][25], bss[16][17];
    for (int i = tid; i < 16 * cT; i += 256) {
        int r = i / cT, c = i % cT;
        L[r][c] = lhs[((size_t)b * cN + m0 + r) * cT + c];
        R[r][c] = rhs[((size_t)b * cN + n0 + r) * cT + c];
    }
    bss[tid >> 4][tid & 15] = bs[(size_t)(m0 + (tid >> 4)) * cN + n0 + (tid & 15)];
    __syncthreads();
    float s = 0.f;
    #pragma unroll
    for (int t = 0; t < cT; t++) s += L[tx][t] * R[ty][t];
    s += bss[tx][ty];
    float sig = 1.f / (1.f + expf(-s));
    Pt[((size_t)b * cN + n0 + ty) * cN + m0 + tx] = f2bf(sig);
}

// ---------------------------------------------------------------------------
// Batched bf16 MFMA GEMM, 128x128 tile, BK=32, 4 waves, 16x16x32 MFMA.
// 1-D grid with XCD-chunked swizzle. Segmented K (512 per segment).
// CM==0: C f32 (doAcc/doRelu). CM==1: C bf16 (doRelu honored).
template<int CM>
__global__ __launch_bounds__(256) void k_mfma_gemm(
    const unsigned short* __restrict__ A, int lda, long long aB, long long segA,
    const unsigned short* __restrict__ Bt, int ldb, long long bB, long long segB,
    void* __restrict__ Cv, int ldc, long long cBs,
    int K, int doAcc, int doRelu, int nx, int ny)
{
    __shared__ unsigned short As[128][40];
    __shared__ unsigned short Bs[128][40];
    int tid = threadIdx.x;
    int nb = gridDim.x;
    int bid = blockIdx.x;
    int xcd = bid & 7, loc = bid >> 3;
    int nid = xcd * (nb >> 3) + loc;
    int z   = nid / (nx * ny);
    int rem = nid % (nx * ny);
    int bm  = (rem / nx) * 128;
    int bn  = (rem % nx) * 128;

    const unsigned short* Ap = A  + (size_t)z * aB;
    const unsigned short* Bp = Bt + (size_t)z * bB;

    int lane = tid & 63, w = tid >> 6;
    int wm = (w >> 1) * 64, wn = (w & 1) * 64;
    int fr = lane & 15, kg = (lane >> 4) * 8;

    f32x4 acc[4][4] = {};

    int c0 = tid, c1 = tid + 256;
    int r0 = c0 >> 2, g0 = (c0 & 3) * 8;
    int r1 = c1 >> 2, g1 = (c1 & 3) * 8;

    for (int k0 = 0; k0 < K; k0 += 32) {
        int seg = k0 >> 9, off = k0 & 511;
        const unsigned short* Aseg = Ap + (size_t)seg * segA;
        const unsigned short* Bseg = Bp + (size_t)seg * segB;
        u16x8 a0 = *(const u16x8*)(Aseg + (size_t)(bm + r0) * lda + off + g0);
        u16x8 a1 = *(const u16x8*)(Aseg + (size_t)(bm + r1) * lda + off + g1);
        u16x8 b0 = *(const u16x8*)(Bseg + (size_t)(bn + r0) * ldb + off + g0);
        u16x8 b1 = *(const u16x8*)(Bseg + (size_t)(bn + r1) * ldb + off + g1);
        __syncthreads();
        *(u16x8*)&As[r0][g0] = a0;
        *(u16x8*)&As[r1][g1] = a1;
        *(u16x8*)&Bs[r0][g0] = b0;
        *(u16x8*)&Bs[r1][g1] = b1;
        __syncthreads();
        s16x8 af[4], bf[4];
        #pragma unroll
        for (int i = 0; i < 4; i++)
            af[i] = *(const s16x8*)&As[wm + i * 16 + fr][kg];
        #pragma unroll
        for (int j = 0; j < 4; j++)
            bf[j] = *(const s16x8*)&Bs[wn + j * 16 + fr][kg];
        #pragma unroll
        for (int i = 0; i < 4; i++)
            #pragma unroll
            for (int j = 0; j < 4; j++)
                acc[i][j] = __builtin_amdgcn_mfma_f32_16x16x32_bf16(
                    af[i], bf[j], acc[i][j], 0, 0, 0);
    }
    int rb = (lane >> 4) * 4;
    if (CM == 0) {
        float* Cp = (float*)Cv + (size_t)z * cBs;
        #pragma unroll
        for (int i = 0; i < 4; i++) {
            int row = bm + wm + i * 16 + rb;
            #pragma unroll
            for (int j = 0; j < 4; j++) {
                int col = bn + wn + j * 16 + fr;
                #pragma unroll
                for (int r = 0; r < 4; r++) {
                    size_t idx = (size_t)(row + r) * ldc + col;
                    float v = acc[i][j][r];
                    if (doAcc) v += Cp[idx];
                    if (doRelu) v = fmaxf(v, 0.f);
                    Cp[idx] = v;
                }
            }
        }
    } else {
        unsigned short* Cp = (unsigned short*)Cv + (size_t)z * cBs;
        #pragma unroll
        for (int i = 0; i < 4; i++) {
            int row = bm + wm + i * 16 + rb;
            #pragma unroll
            for (int j = 0; j < 4; j++) {
                int col = bn + wn + j * 16 + fr;
                #pragma unroll
                for (int r = 0; r < 4; r++) {
                    float v = acc[i][j][r];
                    if (doRelu) v = fmaxf(v, 0.f);
                    Cp[(size_t)(row + r) * ldc + col] = f2bf(v);
                }
            }
        }
    }
}

// ---------------------------------------------------------------------------
__global__ __launch_bounds__(256) void k_softmax512(float* __restrict__ S)
{
    int row = blockIdx.x;
    int tid = threadIdx.x;
    float* p = S + (size_t)row * cN;
    float v0 = p[tid], v1 = p[tid + 256];
    __shared__ float red[256];
    red[tid] = fmaxf(v0, v1);
    __syncthreads();
    for (int off = 128; off > 0; off >>= 1) {
        if (tid < off) red[tid] = fmaxf(red[tid], red[tid + off]);
        __syncthreads();
    }
    float mx = red[0];
    __syncthreads();
    float e0 = expf(v0 - mx), e1 = expf(v1 - mx);
    red[tid] = e0 + e1;
    __syncthreads();
    for (int off = 128; off > 0; off >>= 1) {
        if (tid < off) red[tid] += red[tid + off];
        __syncthreads();
    }
    float inv = 1.f / red[0];
    p[tid] = e0 * inv;
    p[tid + 256] = e1 * inv;
}

// ---------------------------------------------------------------------------
__global__ __launch_bounds__(256) void k_transpose_S(
    const float* __restrict__ S0, unsigned short* __restrict__ St)
{
    int b = blockIdx.z;
    int q0 = blockIdx.y * 64, n0 = blockIdx.x * 64;
    __shared__ float t[64][68];
    int tid = threadIdx.x;
    int r = tid >> 2, grp = (tid & 3) * 16;
    const float* ip = S0 + ((size_t)b * cN + q0 + r) * cN + n0 + grp;
    #pragma unroll
    for (int i = 0; i < 16; i += 4)
        *(float4*)&t[r][grp + i] = *(const float4*)(ip + i);
    __syncthreads();
    int nr = tid & 63, qg = (tid >> 6) * 16;
    unsigned short* op = St + ((size_t)b * cN + n0 + nr) * cN + q0 + qg;
    u16x8 v0, v1;
    #pragma unroll
    for (int i = 0; i < 8; i++) {
        v0[i] = f2bf(t[qg + i][nr]);
        v1[i] = f2bf(t[qg + 8 + i][nr]);
    }
    *(u16x8*)op = v0;
    *(u16x8*)(op + 8) = v1;
}

// ---------------------------------------------------------------------------
// xT2[z][t][n][c] = bf16(x[half*16+z][n][c][t])   (float4 staged)
__global__ __launch_bounds__(64) void k_xtrans_half(
    const float* __restrict__ x, int half, unsigned short* __restrict__ xT2)
{
    int idx = blockIdx.x;            // z*512 + n
    int z = idx >> 9, n = idx & 511;
    int b = half * 16 + z;
    int tid = threadIdx.x;
    __shared__ float xs[64][25];
    const float4* xp4 = (const float4*)(x + (size_t)(b * (size_t)cN + n) * cCT);
    for (int i = tid; i < 384; i += 64) {
        float4 f4 = xp4[i];
        int e = i * 4;
        int c = e / 24, t0 = e % 24;
        xs[c][t0] = f4.x; xs[c][t0 + 1] = f4.y;
        xs[c][t0 + 2] = f4.z; xs[c][t0 + 3] = f4.w;
    }
    __syncthreads();
    unsigned short* op = xT2 + (size_t)z * 786432 + (size_t)n * 64;
    for (int i = tid; i < cCT; i += 64) {
        int t = i >> 6, c = i & 63;
        op[(size_t)t * 32768 + c] = f2bf(xs[c][t]);
    }
}

// ---------------------------------------------------------------------------
// XT via MFMA, direct write to XTt[k][z][f*24+t][n].
__global__ __launch_bounds__(256) void k_xtheta_mfma(
    const unsigned short* __restrict__ xT2,   // [z][t][n][c]
    const unsigned short* __restrict__ ThT,   // [k][f][c]
    unsigned short* __restrict__ XTt,         // [k][z][f*24+t][n]
    long long segX)
{
    __shared__ unsigned short As[128][72];
    __shared__ unsigned short Ths[64][72];
    __shared__ unsigned short Cs[64][136];
    int tid = threadIdx.x;
    int n0 = blockIdx.x * 128;
    int t  = blockIdx.y;
    int z  = blockIdx.z;

    const unsigned short* ap = xT2 + (size_t)z * 786432 + (size_t)t * 32768 + n0 * 64;
    #pragma unroll
    for (int it = 0; it < 4; it++) {
        int v = tid + it * 256;
        int row = v >> 3, c8 = (v & 7) * 8;
        *(u16x8*)&As[row][c8] = *(const u16x8*)(ap + row * 64 + c8);
    }

    int lane = tid & 63, w = tid >> 6;
    int fr = lane & 15, kg = (lane >> 4) * 8;
    int rb = (lane >> 4) * 4;

    for (int k = 0; k < cK; k++) {
        __syncthreads();   // prev Cs/Ths reads + (k=0) A-stage done
        #pragma unroll
        for (int it = 0; it < 2; it++) {
            int vi = tid + it * 256;         // 0..511
            int row = vi >> 3, c8 = (vi & 7) * 8;
            *(u16x8*)&Ths[row][c8] =
                *(const u16x8*)(ThT + (size_t)k * 4096 + row * 64 + c8);
        }
        __syncthreads();
        f32x4 acc[2][4] = {};
        #pragma unroll
        for (int ks = 0; ks < 2; ks++) {
            s16x8 af[2], bf[4];
            #pragma unroll
            for (int i = 0; i < 2; i++)
                af[i] = *(const s16x8*)&As[w * 32 + i * 16 + fr][ks * 32 + kg];
            #pragma unroll
            for (int j = 0; j < 4; j++)
                bf[j] = *(const s16x8*)&Ths[j * 16 + fr][ks * 32 + kg];
            #pragma unroll
            for (int i = 0; i < 2; i++)
                #pragma unroll
                for (int j = 0; j < 4; j++)
                    acc[i][j] = __builtin_amdgcn_mfma_f32_16x16x32_bf16(
                        af[i], bf[j], acc[i][j], 0, 0, 0);
        }
        #pragma unroll
        for (int i = 0; i < 2; i++) {
            int rowb = w * 32 + i * 16 + rb;
            #pragma unroll
            for (int j = 0; j < 4; j++) {
                int f = j * 16 + fr;
                #pragma unroll
                for (int r = 0; r < 4; r++)
                    Cs[f][rowb + r] = f2bf(acc[i][j][r]);
            }
        }
        __syncthreads();
        unsigned short* op = XTt + (size_t)k * segX + (size_t)z * 786432 + n0;
        #pragma unroll
        for (int it = 0; it < 4; it++) {
            int v = tid + it * 256;
            int f = v >> 4, n8 = (v & 15) * 8;
            *(u16x8*)(op + (size_t)(f * 24 + t) * 512 + n8) = *(const u16x8*)&Cs[f][n8];
        }
    }
}

// ---------------------------------------------------------------------------
__global__ void k_convert(const float* __restrict__ a,
                          unsigned short* __restrict__ o, int n)
{
    int i = blockIdx.x * 256 + threadIdx.x;
    if (i < n) o[i] = f2bf(a[i]);
}

// ---------------------------------------------------------------------------
// W2g[f][d*64+fi] = bf16(conv_w[f][fi][0][d])
__global__ void k_wprep(const float* __restrict__ cw,
                        unsigned short* __restrict__ W2g)
{
    int i = blockIdx.x * 256 + threadIdx.x;
    if (i < 64 * 192) {
        int f = i / 192, k = i % 192;
        int d = k >> 6, fi = k & 63;
        W2g[i] = f2bf(cw[f * 192 + fi * 3 + d]);
    }
}

// ---------------------------------------------------------------------------
// ThT[k][f][c] = bf16(Theta[k][c][f])
__global__ void k_thprep(const float* __restrict__ Theta,
                         unsigned short* __restrict__ ThT)
{
    int i = blockIdx.x * 256 + threadIdx.x;
    if (i < cK * 64 * 64) {
        int k = i >> 12, r = i & 4095;
        int f = r >> 6, c = r & 63;
        ThT[i] = f2bf(Theta[k * 4096 + c * 64 + f]);
    }
}

// ---------------------------------------------------------------------------
// partial hU1 from bf16 h
__global__ __launch_bounds__(256) void k_hU1_part(
    const unsigned short* __restrict__ h, const float* __restrict__ U1,
    float* __restrict__ part)
{
    int b = blockIdx.x, nc = blockIdx.y;
    int tid = threadIdx.x;
    int f = tid & 63, q = tid >> 6;
    float acc[24];
    #pragma unroll
    for (int t = 0; t < 24; t++) acc[t] = 0.f;
    for (int n = nc * 32 + q; n < nc * 32 + 32; n += 4) {
        float u = U1[n];
        const u16x8* hp = (const u16x8*)(h + (((size_t)b * cN + n) * cF + f) * cT);
        #pragma unroll
        for (int v8 = 0; v8 < 3; v8++) {
            u16x8 hv = hp[v8];
            #pragma unroll
            for (int e = 0; e < 8; e++)
                acc[v8 * 8 + e] += u * bf2f(hv[e]);
        }
    }
    __shared__ float ps[4][64][25];
    #pragma unroll
    for (int t = 0; t < 24; t++) ps[q][f][t] = acc[t];
    __syncthreads();
    for (int i = tid; i < cFT; i += 256) {
        int f2 = i / cT, t2 = i % cT;
        float s = ps[0][f2][t2] + ps[1][f2][t2] + ps[2][f2][t2] + ps[3][f2][t2];
        part[(((size_t)b * 16 + nc) * cF + f2) * cT + t2] = s;
    }
}

// ---------------------------------------------------------------------------
__global__ __launch_bounds__(256) void k_lhs_t(
    const float* __restrict__ part, const float* __restrict__ U2,
    float* __restrict__ lhs_t)
{
    int b = blockIdx.x, ch = blockIdx.y;
    int tid = threadIdx.x;
    __shared__ float hu[1536];
    for (int i = tid; i < 1536; i += 256) {
        float s = 0.f;
        for (int nc = 0; nc < 16; nc++)
            s += part[((size_t)b * 16 + nc) * 1536 + i];
        hu[i] = s;
    }
    __syncthreads();
    int nn0 = ch * 128;
    for (int i = tid; i < cT * 128; i += 256) {
        int t = i / 128, nn = nn0 + (i % 128);
        float s = 0.f;
        #pragma unroll
        for (int f = 0; f < 64; f++) s += hu[f * cT + t] * U2[(size_t)f * cN + nn];
        lhs_t[((size_t)b * cT + t) * cN + nn] = s;
    }
}

// ---------------------------------------------------------------------------
// rhs_t from bf16 h
__global__ __launch_bounds__(64) void k_rhs_t(
    const unsigned short* __restrict__ h, const float* __restrict__ U3,
    float* __restrict__ rhs_t)
{
    int bn = blockIdx.x;
    int f = threadIdx.x;
    __shared__ float sl[64][25];
    const u16x8* hp = (const u16x8*)(h + (size_t)bn * cFT + f * cT);
    float u = U3[f];
    #pragma unroll
    for (int v8 = 0; v8 < 3; v8++) {
        u16x8 hv = hp[v8];
        #pragma unroll
        for (int e = 0; e < 8; e++)
            sl[f][v8 * 8 + e] = u * bf2f(hv[e]);
    }
    __syncthreads();
    if (f < cT) {
        float s = 0.f;
        #pragma unroll
        for (int c = 0; c < 64; c++) s += sl[c][f];
        rhs_t[(size_t)bn * cT + f] = s;
    }
}

// ---------------------------------------------------------------------------
// rhs_t[b] staged in LDS (512x24 f32 = 48KB)
__global__ __launch_bounds__(576) void k_E(
    const float* __restrict__ lhs_t, const float* __restrict__ rhs_t,
    const float* __restrict__ be, const float* __restrict__ Ve,
    float* __restrict__ E)
{
    int b = blockIdx.x;
    int tid = threadIdx.x;
    int i = tid / 24, j = tid % 24;
    __shared__ float rs[12288];
    __shared__ float ps[24][25];
    __shared__ float er[24][25];
    __shared__ float mrow[24], srow[24];
    const float* rp = rhs_t + (size_t)b * 12288;
    for (int v = tid; v < 12288; v += 576) rs[v] = rp[v];
    __syncthreads();
    const float* lp = lhs_t + ((size_t)b * cT + i) * cN;
    float s = 0.f;
    for (int n = 0; n < cN; n++) s += lp[n] * rs[n * cT + j];
    s += be[i * cT + j];
    ps[i][j] = 1.f / (1.f + expf(-s));
    __syncthreads();
    float e = 0.f;
    #pragma unroll
    for (int ss = 0; ss < cT; ss++) e += Ve[i * cT + ss] * ps[ss][j];
    er[i][j] = e;
    __syncthreads();
    if (j == 0) {
        float m = -1e30f;
        for (int r = 0; r < cT; r++) m = fmaxf(m, er[i][r]);
        float sm = 0.f;
        for (int r = 0; r < cT; r++) sm += expf(er[i][r] - m);
        mrow[i] = m;
        srow[i] = sm;
    }
    __syncthreads();
    E[(size_t)b * cT * cT + i * cT + j] = expf(er[i][j] - mrow[i]) / srow[i];
}

// ---------------------------------------------------------------------------
// MFMA temporal mixing: hT[b,n,so,f] = sum_t h[b,n,f,t] * E[b][t][so].
__global__ __launch_bounds__(256) void k_tmix_mfma(
    const unsigned short* __restrict__ h,   // hbf [b,n,f,t] bf16
    const float* __restrict__ E,            // [b][24][24]
    unsigned short* __restrict__ hT)        // [b,n,t,f] bf16
{
    __shared__ float Es[24][25];
    __shared__ unsigned short bounce[8][24][64];
    int tid = threadIdx.x;
    int blk = blockIdx.x;            // 2048
    int b = blk >> 6;
    int n0 = (blk & 63) * 8;
    for (int i = tid; i < 576; i += 256)
        Es[i / 24][i % 24] = E[(size_t)b * 576 + i];
    __syncthreads();

    int lane = tid & 63, w = tid >> 6;
    int fr = lane & 15, g = lane >> 4;

    s16x8 afr[2];
    #pragma unroll
    for (int m = 0; m < 2; m++) {
        int so = m * 16 + fr;
        u16x8 a = {};
        if (so < 24 && g < 3) {
            #pragma unroll
            for (int e = 0; e < 8; e++)
                a[e] = f2bf(Es[g * 8 + e][so]);
        }
        afr[m] = *(s16x8*)&a;
    }

    f32x4 zero = {};
    #pragma unroll
    for (int ss = 0; ss < 2; ss++) {
        int s = w * 2 + ss;
        const unsigned short* hp = h + ((size_t)b * cN + n0 + s) * cFT;
        #pragma unroll
        for (int jj = 0; jj < 4; jj++) {
            u16x8 bfrag = {};
            if (g < 3)
                bfrag = *(const u16x8*)(hp + (jj * 16 + fr) * 24 + g * 8);
            s16x8 bf = *(s16x8*)&bfrag;
            #pragma unroll
            for (int m = 0; m < 2; m++) {
                f32x4 c = __builtin_amdgcn_mfma_f32_16x16x32_bf16(
                    afr[m], bf, zero, 0, 0, 0);
                #pragma unroll
                for (int r = 0; r < 4; r++) {
                    int so = m * 16 + g * 4 + r;
                    if (so < 24)
                        bounce[s][so][jj * 16 + fr] = f2bf(c[r]);
                }
            }
        }
    }
    __syncthreads();
    unsigned short* op = hT + ((size_t)b * cN + n0) * cFT;
    #pragma unroll
    for (int it = 0; it < 6; it++) {
        int i = tid + it * 256;
        *(u16x8*)(op + i * 8) = *(const u16x8*)&bounce[0][0][i * 8];
    }
}

// ---------------------------------------------------------------------------
// MFMA conv(1,3) + bias + residual(x) + LayerNorm over F. float4 stores.
__global__ __launch_bounds__(256) void k_convmfma(
    const unsigned short* __restrict__ hT,   // [b,n,t,f] bf16
    const float* __restrict__ x,             // [b,n,c,t] f32
    const unsigned short* __restrict__ W2g,  // [f][192] bf16, k=(d*64+fi)
    const float* __restrict__ cb,
    const float* __restrict__ lnw, const float* __restrict__ lnb,
    float* __restrict__ out)                 // [b,n,f,t] f32
{
    __shared__ unsigned short Hs[8][26][72];
    __shared__ unsigned short Ws[64][200];
    int tid = threadIdx.x;
    int blk = blockIdx.x;
    int b = blk >> 6;
    int n0 = (blk & 63) * 8;
    const unsigned short* hp = hT + ((size_t)b * cN + n0) * cFT;

    #pragma unroll
    for (int it = 0; it < 6; it++) {
        int v = tid + it * 256;
        int s = v / 192;
        int r = v % 192;
        int t = r >> 3, f0 = (r & 7) * 8;
        u16x8 val = *(const u16x8*)(hp + (size_t)s * cFT + t * 64 + f0);
        *(u16x8*)&Hs[s][1 + t][f0] = val;
    }
    if (tid < 144) {
        int s = tid / 18, rm = tid % 18;
        int side = rm / 9, c8 = (rm % 9) * 8;
        u16x8 z = {};
        *(u16x8*)&Hs[s][side * 25][c8] = z;
    }
    #pragma unroll
    for (int it = 0; it < 48; it++) {
        int i = tid + it * 256;
        Ws[i / 192][i % 192] = W2g[i];
    }
    __syncthreads();

    int lane = tid & 63, w = tid >> 6;
    int fr = lane & 15, kgrp = lane >> 4;
    f32x4 acc[3][4] = {};

    int sA[3], tA[3];
    #pragma unroll
    for (int mi = 0; mi < 3; mi++) {
        int row = (w * 3 + mi) * 16 + fr;
        sA[mi] = row / 24; tA[mi] = row % 24;
    }
    #pragma unroll
    for (int ks = 0; ks < 6; ks++) {
        int d = ks >> 1;
        int fi0 = (ks & 1) * 32 + kgrp * 8;
        s16x8 bf[4];
        #pragma unroll
        for (int j = 0; j < 4; j++)
            bf[j] = *(const s16x8*)&Ws[j * 16 + fr][ks * 32 + kgrp * 8];
        #pragma unroll
        for (int mi = 0; mi < 3; mi++) {
            s16x8 af = *(const s16x8*)&Hs[sA[mi]][tA[mi] + d][fi0];
            #pragma unroll
            for (int j = 0; j < 4; j++)
                acc[mi][j] = __builtin_amdgcn_mfma_f32_16x16x32_bf16(
                    af, bf[j], acc[mi][j], 0, 0, 0);
        }
    }

    float lnw_v[4], lnb_v[4], cb_v[4];
    #pragma unroll
    for (int j = 0; j < 4; j++) {
        int f = j * 16 + fr;
        lnw_v[j] = lnw[f]; lnb_v[j] = lnb[f]; cb_v[j] = cb[f];
    }
    #pragma unroll
    for (int mi = 0; mi < 3; mi++) {
        int rowbase = (w * 3 + mi) * 16 + kgrp * 4;
        int sB = rowbase / 24, tb = rowbase % 24;
        size_t slab = ((size_t)b * cN + n0 + sB) * 64;
        float outv[4][4];   // [j][r]
        #pragma unroll
        for (int r = 0; r < 4; r++) {
            int t = tb + r;
            float v[4], s1 = 0.f, s2 = 0.f;
            #pragma unroll
            for (int j = 0; j < 4; j++) {
                float xres = x[(slab + j * 16 + fr) * 24 + t];
                v[j] = acc[mi][j][r] + cb_v[j] + xres;
                s1 += v[j];
                s2 += v[j] * v[j];
            }
            #pragma unroll
            for (int off = 1; off < 16; off <<= 1) {
                s1 += __shfl_xor(s1, off, 64);
                s2 += __shfl_xor(s2, off, 64);
            }
            float mean = s1 * (1.f / 64.f);
            float var = s2 * (1.f / 64.f) - mean * mean;
            float rstd = rsqrtf(var + 1e-5f);
            #pragma unroll
            for (int j = 0; j < 4; j++)
                outv[j][r] = (v[j] - mean) * rstd * lnw_v[j] + lnb_v[j];
        }
        #pragma unroll
        for (int j = 0; j < 4; j++) {
            float4 o = make_float4(outv[j][0], outv[j][1], outv[j][2], outv[j][3]);
            *(float4*)&out[(slab + j * 16 + fr) * 24 + tb] = o;
        }
    }
}

// ---------------------------------------------------------------------------
extern "C" void kernel_launch(void* const* d_in, const int* in_sizes, int n_in,
                              void* d_out, int out_size, void* d_ws, size_t ws_size,
                              hipStream_t stream)
{
    const float* x     = (const float*)d_in[0];
    const float* cheb  = (const float*)d_in[1];
    const float* W1    = (const float*)d_in[2];
    const float* W2    = (const float*)d_in[3];
    const float* W3    = (const float*)d_in[4];
    const float* bs    = (const float*)d_in[5];
    const float* Vs    = (const float*)d_in[6];
    const float* U1    = (const float*)d_in[7];
    const float* U2    = (const float*)d_in[8];
    const float* U3    = (const float*)d_in[9];
    const float* be    = (const float*)d_in[10];
    const float* Ve    = (const float*)d_in[11];
    const float* Theta = (const float*)d_in[12];
    const float* cw    = (const float*)d_in[13];
    const float* cbp   = (const float*)d_in[14];
    const float* lnw   = (const float*)d_in[15];
    const float* lnb   = (const float*)d_in[16];
    float* out = (float*)d_out;
    float* ws  = (float*)d_ws;

    // workspace layout: round-16 layout (peak ws 138.5 MB).
    // Wk REINDEXED to [zz][k][512][512] (same size) for merged W-GEMM.
    unsigned short* Vs_bf   = (unsigned short*)(ws);              // 131072 f32
    unsigned short* cheb_bf = (unsigned short*)(ws + 131072);     // 393216 f32
    float*  lhs  = ws + 524288;     // 393216 (also lhs_t)
    float*  rhs  = ws + 917504;     // 393216 (also rhs_t)
    float*  part = ws + 1310720;    // 786432
    unsigned short* ThT = (unsigned short*)(ws + 1310720);        // overlays part
    float*  Ebuf = ws + 2097152;    // 18432
    unsigned short* W2g = (unsigned short*)(ws + 2115584);        // 12288 u16
    unsigned short* St  = (unsigned short*)(ws + 2124800);        // 8388608 u16
    unsigned short* Wk  = (unsigned short*)(ws + 6319104);        // 12582912 u16, [zz][k][512][512]
    unsigned short* XTt = (unsigned short*)(ws + 12610560);       // 37748736 u16
    unsigned short* Pt  = (unsigned short*)(ws + 12610560);       // overlay (dead before XTt)
    float*          S0  = ws + 22047744;                          // 8388608 f32 (dead before XTt)
    unsigned short* xT2 = (unsigned short*)(ws + 31484928);       // 6291456 u16 (per half)
    unsigned short* hbf = (unsigned short*)out;                   // 25165824 u16 = 50 MB of d_out
    unsigned short* hT  = XTt;                                    // reuse after GEMM loop

    const long long NN2 = (long long)cN * cN;        // 262144
    const long long NFT = (long long)cN * cFT;       // 786432
    const long long segX = 16LL * 1536 * 512;        // XTt k-segment

    k_convert<<<1024, 256, 0, stream>>>(Vs, Vs_bf, 262144);
    k_convert<<<3072, 256, 0, stream>>>(cheb, cheb_bf, 786432);
    k_wprep<<<48, 256, 0, stream>>>(cw, W2g);
    k_thprep<<<48, 256, 0, stream>>>(Theta, ThT);

    // spatial attention
    k_spatial_lr<<<cB * cN / 4, 256, 0, stream>>>(x, W1, W2, W3, lhs, rhs);
    k_product_t<<<dim3(32, 32, cB), dim3(16, 16), 0, stream>>>(lhs, rhs, bs, Pt);
    // S0 = Vs @ P: 512 blocks (1-D swizzled)
    k_mfma_gemm<0><<<512, 256, 0, stream>>>(
        Vs_bf, 512, 0LL, 0LL, Pt, 512, NN2, 0LL, S0, 512, NN2, 512, 0, 0, 4, 4);
    k_softmax512<<<cB * cN, 256, 0, stream>>>(S0);
    k_transpose_S<<<dim3(8, 8, cB), 256, 0, stream>>>(S0, St);

    // Cheb conv, batch-halved with fused-K final GEMM -> h (bf16+relu) in d_out
    for (int half = 0; half < 2; half++) {
        k_xtrans_half<<<16 * 512, 64, 0, stream>>>(x, half, xT2);
        k_xtheta_mfma<<<dim3(4, 24, 16), 256, 0, stream>>>(xT2, ThT, XTt, segX);
        // W' = cheb'(1536x512) @ S_half: one merged GEMM, 12x4x16 = 768 blocks.
        // C rows m = k*512+r land at Wk[zz][k][r][:] (cBs = 3*NN2).
        k_mfma_gemm<1><<<768, 256, 0, stream>>>(
            cheb_bf, 512, 0LL, 0LL,
            St + (size_t)half * 16 * NN2, 512, NN2, 0LL,
            Wk, 512, 3 * NN2, 512, 0, 0, 4, 12);
        // h_half = relu(sum_k W_k @ XT_k): K=1536 segmented, A seg = k slab.
        k_mfma_gemm<1><<<768, 256, 0, stream>>>(
            Wk, 512, 3 * NN2, NN2, XTt, 512, 786432LL, segX,
            hbf + (size_t)half * 16 * NFT, 1536, NFT, 1536, 0, 1, 12, 4);
    }

    // temporal attention (reads h = hbf bf16; ThT dead from here)
    k_hU1_part<<<dim3(cB, 16), 256, 0, stream>>>(hbf, U1, part);
    k_rhs_t<<<cB * cN, 64, 0, stream>>>(hbf, U3, rhs);
    k_lhs_t<<<dim3(cB, 4), 256, 0, stream>>>(part, U2, lhs);
    k_E<<<cB, 576, 0, stream>>>(lhs, rhs, be, Ve, Ebuf);

    // temporal mixing via MFMA -> hT (bf16, [t,f]; hbf dead after), conv+LN -> out
    k_tmix_mfma<<<2048, 256, 0, stream>>>(hbf, Ebuf, hT);
    k_convmfma<<<2048, 256, 0, stream>>>(hT, x, W2g, cbp, lnw, lnb, out);
}

// Round 18
// 466.636 us; speedup vs baseline: 2.7241x; 1.0220x over previous
//
#include <hip/hip_runtime.h>

// Problem constants
constexpr int cB = 32, cN = 512, cC = 64, cT = 24, cK = 3, cF = 64;
constexpr int cCT = cC * cT;   // 1536
constexpr int cFT = cF * cT;   // 1536

typedef __attribute__((ext_vector_type(8))) short s16x8;            // MFMA bf16 frag
typedef __attribute__((ext_vector_type(8))) unsigned short u16x8;   // 16B load/store
typedef __attribute__((ext_vector_type(4))) float f32x4;            // MFMA acc

__device__ inline unsigned short f2bf(float f) {
    union { float f; unsigned int u; } v; v.f = f;
    unsigned int r = v.u + 0x7FFFu + ((v.u >> 16) & 1u);
    return (unsigned short)(r >> 16);
}
__device__ inline float bf2f(unsigned short u) {
    union { unsigned int i; float f; } v; v.i = ((unsigned int)u) << 16;
    return v.f;
}

// ---------------------------------------------------------------------------
// 4 slabs per 256-thread block; float4 x staging.
__global__ __launch_bounds__(256) void k_spatial_lr(
    const float* __restrict__ x, const float* __restrict__ W1,
    const float* __restrict__ W2, const float* __restrict__ W3,
    float* __restrict__ lhs, float* __restrict__ rhs)
{
    int tid = threadIdx.x;
    int bn0 = blockIdx.x * 4;
    __shared__ float xs[4][64][25];
    __shared__ float a_sh[4][64];
    const float4* xp4 = (const float4*)(x + (size_t)bn0 * cCT);
    for (int v = tid; v < 1536; v += 256) {
        int sl = v / 384, i = v % 384;
        float4 f4 = xp4[sl * 384 + i];
        int e = i * 4;
        int c = e / 24, t0 = e % 24;
        xs[sl][c][t0] = f4.x; xs[sl][c][t0 + 1] = f4.y;
        xs[sl][c][t0 + 2] = f4.z; xs[sl][c][t0 + 3] = f4.w;
    }
    __syncthreads();
    int sl = tid >> 6, c = tid & 63;
    float s = 0.f;
    #pragma unroll
    for (int t = 0; t < cT; t++) s += xs[sl][c][t] * W1[t];
    a_sh[sl][c] = s;
    __syncthreads();
    if (c < cT) {
        float l = 0.f, r = 0.f;
        for (int cp = 0; cp < cC; cp++) {
            l += a_sh[sl][cp] * W2[cp * cT + c];
            r += xs[sl][cp][c] * W3[cp];
        }
        lhs[(size_t)(bn0 + sl) * cT + c] = l;
        rhs[(size_t)(bn0 + sl) * cT + c] = r;
    }
}

// ---------------------------------------------------------------------------
// Pt[b,n,m] = bf16(sigmoid(sum_t lhs[b,m,t]*rhs[b,n,t] + bs[m,n]))  (transposed)
__global__ __launch_bounds__(256) void k_product_t(
    const float* __restrict__ lhs, const float* __restrict__ rhs,
    const float* __restrict__ bs, unsigned short* __restrict__ Pt)
{
    int b = blockIdx.z;
    int m0 = blockIdx.y * 16, n0 = blockIdx.x * 16;
    int tx = threadIdx.x, ty = threadIdx.y;
    int tid = ty * 16 + tx;
    __shared__ float L[16][25], R[16][25], bss[16][17];
    for (int i = tid; i < 16 * cT; i += 256) {
        int r = i / cT, c = i % cT;
        L[r][c] = lhs[((size_t)b * cN + m0 + r) * cT + c];
        R[r][c] = rhs[((size_t)b * cN + n0 + r) * cT + c];
    }
    bss[tid >> 4][tid & 15] = bs[(size_t)(m0 + (tid >> 4)) * cN + n0 + (tid & 15)];
    __syncthreads();
    float s = 0.f;
    #pragma unroll
    for (int t = 0; t < cT; t++) s += L[tx][t] * R[ty][t];
    s += bss[tx][ty];
    float sig = 1.f / (1.f + expf(-s));
    Pt[((size_t)b * cN + n0 + ty) * cN + m0 + tx] = f2bf(sig);
}

// ---------------------------------------------------------------------------
// Batched bf16 MFMA GEMM, 128x128 tile, BK=32, 4 waves, 16x16x32 MFMA.
// ASYNC global_load_lds staging (m97 structure): linear LDS [128][32], each
// wave stages 32 rows via 2x 1024B chunks. 1-D grid, XCD-chunked swizzle.
// Segmented K (512 per segment). CM==0: C f32. CM==1: C bf16.
template<int CM>
__global__ __launch_bounds__(256) void k_mfma_gemm(
    const unsigned short* __restrict__ A, int lda, long long aB, long long segA,
    const unsigned short* __restrict__ Bt, int ldb, long long bB, long long segB,
    void* __restrict__ Cv, int ldc, long long cBs,
    int K, int doAcc, int doRelu, int nx, int ny)
{
    __shared__ unsigned short As[128 * 32];
    __shared__ unsigned short Bs[128 * 32];
    int tid = threadIdx.x;
    int nb = gridDim.x;
    int bid = blockIdx.x;
    int xcd = bid & 7, loc = bid >> 3;
    int nid = xcd * (nb >> 3) + loc;
    int z   = nid / (nx * ny);
    int rem = nid % (nx * ny);
    int bm  = (rem / nx) * 128;
    int bn  = (rem % nx) * 128;

    const unsigned short* Ap = A  + (size_t)z * aB;
    const unsigned short* Bp = Bt + (size_t)z * bB;

    int lane = tid & 63, w = tid >> 6;
    int wm = (w >> 1) * 64, wn = (w & 1) * 64;
    int fr = lane & 15, kg = (lane >> 4) * 8;

    int srow = lane >> 2;          // 0..15
    int scol = (lane & 3) * 8;     // 0,8,16,24

    f32x4 acc[4][4] = {};

    for (int k0 = 0; k0 < K; k0 += 32) {
        int seg = k0 >> 9, off = k0 & 511;
        const unsigned short* Aseg = Ap + (size_t)seg * segA;
        const unsigned short* Bseg = Bp + (size_t)seg * segB;
        __syncthreads();   // prior iter's ds_reads complete before overwrite
        #pragma unroll
        for (int q = 0; q < 2; q++) {
            int r0 = w * 32 + q * 16;
            __builtin_amdgcn_global_load_lds(
                (const __attribute__((address_space(1))) unsigned int*)
                    (Aseg + (size_t)(bm + r0 + srow) * lda + off + scol),
                (__attribute__((address_space(3))) unsigned int*)
                    &As[r0 * 32 + lane * 8],
                16, 0, 0);
            __builtin_amdgcn_global_load_lds(
                (const __attribute__((address_space(1))) unsigned int*)
                    (Bseg + (size_t)(bn + r0 + srow) * ldb + off + scol),
                (__attribute__((address_space(3))) unsigned int*)
                    &Bs[r0 * 32 + lane * 8],
                16, 0, 0);
        }
        __syncthreads();   // drains vmcnt -> LDS data visible
        s16x8 af[4], bf[4];
        #pragma unroll
        for (int i = 0; i < 4; i++)
            af[i] = *(const s16x8*)&As[(wm + i * 16 + fr) * 32 + kg];
        #pragma unroll
        for (int j = 0; j < 4; j++)
            bf[j] = *(const s16x8*)&Bs[(wn + j * 16 + fr) * 32 + kg];
        #pragma unroll
        for (int i = 0; i < 4; i++)
            #pragma unroll
            for (int j = 0; j < 4; j++)
                acc[i][j] = __builtin_amdgcn_mfma_f32_16x16x32_bf16(
                    af[i], bf[j], acc[i][j], 0, 0, 0);
    }
    int rb = (lane >> 4) * 4;
    if (CM == 0) {
        float* Cp = (float*)Cv + (size_t)z * cBs;
        #pragma unroll
        for (int i = 0; i < 4; i++) {
            int row = bm + wm + i * 16 + rb;
            #pragma unroll
            for (int j = 0; j < 4; j++) {
                int col = bn + wn + j * 16 + fr;
                #pragma unroll
                for (int r = 0; r < 4; r++) {
                    size_t idx = (size_t)(row + r) * ldc + col;
                    float v = acc[i][j][r];
                    if (doAcc) v += Cp[idx];
                    if (doRelu) v = fmaxf(v, 0.f);
                    Cp[idx] = v;
                }
            }
        }
    } else {
        unsigned short* Cp = (unsigned short*)Cv + (size_t)z * cBs;
        #pragma unroll
        for (int i = 0; i < 4; i++) {
            int row = bm + wm + i * 16 + rb;
            #pragma unroll
            for (int j = 0; j < 4; j++) {
                int col = bn + wn + j * 16 + fr;
                #pragma unroll
                for (int r = 0; r < 4; r++) {
                    float v = acc[i][j][r];
                    if (doRelu) v = fmaxf(v, 0.f);
                    Cp[(size_t)(row + r) * ldc + col] = f2bf(v);
                }
            }
        }
    }
}

// ---------------------------------------------------------------------------
__global__ __launch_bounds__(256) void k_softmax512(float* __restrict__ S)
{
    int row = blockIdx.x;
    int tid = threadIdx.x;
    float* p = S + (size_t)row * cN;
    float v0 = p[tid], v1 = p[tid + 256];
    __shared__ float red[256];
    red[tid] = fmaxf(v0, v1);
    __syncthreads();
    for (int off = 128; off > 0; off >>= 1) {
        if (tid < off) red[tid] = fmaxf(red[tid], red[tid + off]);
        __syncthreads();
    }
    float mx = red[0];
    __syncthreads();
    float e0 = expf(v0 - mx), e1 = expf(v1 - mx);
    red[tid] = e0 + e1;
    __syncthreads();
    for (int off = 128; off > 0; off >>= 1) {
        if (tid < off) red[tid] += red[tid + off];
        __syncthreads();
    }
    float inv = 1.f / red[0];
    p[tid] = e0 * inv;
    p[tid + 256] = e1 * inv;
}

// ---------------------------------------------------------------------------
__global__ __launch_bounds__(256) void k_transpose_S(
    const float* __restrict__ S0, unsigned short* __restrict__ St)
{
    int b = blockIdx.z;
    int q0 = blockIdx.y * 64, n0 = blockIdx.x * 64;
    __shared__ float t[64][68];
    int tid = threadIdx.x;
    int r = tid >> 2, grp = (tid & 3) * 16;
    const float* ip = S0 + ((size_t)b * cN + q0 + r) * cN + n0 + grp;
    #pragma unroll
    for (int i = 0; i < 16; i += 4)
        *(float4*)&t[r][grp + i] = *(const float4*)(ip + i);
    __syncthreads();
    int nr = tid & 63, qg = (tid >> 6) * 16;
    unsigned short* op = St + ((size_t)b * cN + n0 + nr) * cN + q0 + qg;
    u16x8 v0, v1;
    #pragma unroll
    for (int i = 0; i < 8; i++) {
        v0[i] = f2bf(t[qg + i][nr]);
        v1[i] = f2bf(t[qg + 8 + i][nr]);
    }
    *(u16x8*)op = v0;
    *(u16x8*)(op + 8) = v1;
}

// ---------------------------------------------------------------------------
// xT2[z][t][n][c] = bf16(x[half*16+z][n][c][t])   (float4 staged)
__global__ __launch_bounds__(64) void k_xtrans_half(
    const float* __restrict__ x, int half, unsigned short* __restrict__ xT2)
{
    int idx = blockIdx.x;            // z*512 + n
    int z = idx >> 9, n = idx & 511;
    int b = half * 16 + z;
    int tid = threadIdx.x;
    __shared__ float xs[64][25];
    const float4* xp4 = (const float4*)(x + (size_t)(b * (size_t)cN + n) * cCT);
    for (int i = tid; i < 384; i += 64) {
        float4 f4 = xp4[i];
        int e = i * 4;
        int c = e / 24, t0 = e % 24;
        xs[c][t0] = f4.x; xs[c][t0 + 1] = f4.y;
        xs[c][t0 + 2] = f4.z; xs[c][t0 + 3] = f4.w;
    }
    __syncthreads();
    unsigned short* op = xT2 + (size_t)z * 786432 + (size_t)n * 64;
    for (int i = tid; i < cCT; i += 64) {
        int t = i >> 6, c = i & 63;
        op[(size_t)t * 32768 + c] = f2bf(xs[c][t]);
    }
}

// ---------------------------------------------------------------------------
// XT via MFMA, direct write to XTt[k][z][f*24+t][n].
__global__ __launch_bounds__(256) void k_xtheta_mfma(
    const unsigned short* __restrict__ xT2,   // [z][t][n][c]
    const unsigned short* __restrict__ ThT,   // [k][f][c]
    unsigned short* __restrict__ XTt,         // [k][z][f*24+t][n]
    long long segX)
{
    __shared__ unsigned short As[128][72];
    __shared__ unsigned short Ths[64][72];
    __shared__ unsigned short Cs[64][136];
    int tid = threadIdx.x;
    int n0 = blockIdx.x * 128;
    int t  = blockIdx.y;
    int z  = blockIdx.z;

    const unsigned short* ap = xT2 + (size_t)z * 786432 + (size_t)t * 32768 + n0 * 64;
    #pragma unroll
    for (int it = 0; it < 4; it++) {
        int v = tid + it * 256;
        int row = v >> 3, c8 = (v & 7) * 8;
        *(u16x8*)&As[row][c8] = *(const u16x8*)(ap + row * 64 + c8);
    }

    int lane = tid & 63, w = tid >> 6;
    int fr = lane & 15, kg = (lane >> 4) * 8;
    int rb = (lane >> 4) * 4;

    for (int k = 0; k < cK; k++) {
        __syncthreads();   // prev Cs/Ths reads + (k=0) A-stage done
        #pragma unroll
        for (int it = 0; it < 2; it++) {
            int vi = tid + it * 256;         // 0..511
            int row = vi >> 3, c8 = (vi & 7) * 8;
            *(u16x8*)&Ths[row][c8] =
                *(const u16x8*)(ThT + (size_t)k * 4096 + row * 64 + c8);
        }
        __syncthreads();
        f32x4 acc[2][4] = {};
        #pragma unroll
        for (int ks = 0; ks < 2; ks++) {
            s16x8 af[2], bf[4];
            #pragma unroll
            for (int i = 0; i < 2; i++)
                af[i] = *(const s16x8*)&As[w * 32 + i * 16 + fr][ks * 32 + kg];
            #pragma unroll
            for (int j = 0; j < 4; j++)
                bf[j] = *(const s16x8*)&Ths[j * 16 + fr][ks * 32 + kg];
            #pragma unroll
            for (int i = 0; i < 2; i++)
                #pragma unroll
                for (int j = 0; j < 4; j++)
                    acc[i][j] = __builtin_amdgcn_mfma_f32_16x16x32_bf16(
                        af[i], bf[j], acc[i][j], 0, 0, 0);
        }
        #pragma unroll
        for (int i = 0; i < 2; i++) {
            int rowb = w * 32 + i * 16 + rb;
            #pragma unroll
            for (int j = 0; j < 4; j++) {
                int f = j * 16 + fr;
                #pragma unroll
                for (int r = 0; r < 4; r++)
                    Cs[f][rowb + r] = f2bf(acc[i][j][r]);
            }
        }
        __syncthreads();
        unsigned short* op = XTt + (size_t)k * segX + (size_t)z * 786432 + n0;
        #pragma unroll
        for (int it = 0; it < 4; it++) {
            int v = tid + it * 256;
            int f = v >> 4, n8 = (v & 15) * 8;
            *(u16x8*)(op + (size_t)(f * 24 + t) * 512 + n8) = *(const u16x8*)&Cs[f][n8];
        }
    }
}

// ---------------------------------------------------------------------------
__global__ void k_convert(const float* __restrict__ a,
                          unsigned short* __restrict__ o, int n)
{
    int i = blockIdx.x * 256 + threadIdx.x;
    if (i < n) o[i] = f2bf(a[i]);
}

// ---------------------------------------------------------------------------
// W2g[f][d*64+fi] = bf16(conv_w[f][fi][0][d])
__global__ void k_wprep(const float* __restrict__ cw,
                        unsigned short* __restrict__ W2g)
{
    int i = blockIdx.x * 256 + threadIdx.x;
    if (i < 64 * 192) {
        int f = i / 192, k = i % 192;
        int d = k >> 6, fi = k & 63;
        W2g[i] = f2bf(cw[f * 192 + fi * 3 + d]);
    }
}

// ---------------------------------------------------------------------------
// ThT[k][f][c] = bf16(Theta[k][c][f])
__global__ void k_thprep(const float* __restrict__ Theta,
                         unsigned short* __restrict__ ThT)
{
    int i = blockIdx.x * 256 + threadIdx.x;
    if (i < cK * 64 * 64) {
        int k = i >> 12, r = i & 4095;
        int f = r >> 6, c = r & 63;
        ThT[i] = f2bf(Theta[k * 4096 + c * 64 + f]);
    }
}

// ---------------------------------------------------------------------------
// partial hU1 from bf16 h
__global__ __launch_bounds__(256) void k_hU1_part(
    const unsigned short* __restrict__ h, const float* __restrict__ U1,
    float* __restrict__ part)
{
    int b = blockIdx.x, nc = blockIdx.y;
    int tid = threadIdx.x;
    int f = tid & 63, q = tid >> 6;
    float acc[24];
    #pragma unroll
    for (int t = 0; t < 24; t++) acc[t] = 0.f;
    for (int n = nc * 32 + q; n < nc * 32 + 32; n += 4) {
        float u = U1[n];
        const u16x8* hp = (const u16x8*)(h + (((size_t)b * cN + n) * cF + f) * cT);
        #pragma unroll
        for (int v8 = 0; v8 < 3; v8++) {
            u16x8 hv = hp[v8];
            #pragma unroll
            for (int e = 0; e < 8; e++)
                acc[v8 * 8 + e] += u * bf2f(hv[e]);
        }
    }
    __shared__ float ps[4][64][25];
    #pragma unroll
    for (int t = 0; t < 24; t++) ps[q][f][t] = acc[t];
    __syncthreads();
    for (int i = tid; i < cFT; i += 256) {
        int f2 = i / cT, t2 = i % cT;
        float s = ps[0][f2][t2] + ps[1][f2][t2] + ps[2][f2][t2] + ps[3][f2][t2];
        part[(((size_t)b * 16 + nc) * cF + f2) * cT + t2] = s;
    }
}

// ---------------------------------------------------------------------------
__global__ __launch_bounds__(256) void k_lhs_t(
    const float* __restrict__ part, const float* __restrict__ U2,
    float* __restrict__ lhs_t)
{
    int b = blockIdx.x, ch = blockIdx.y;
    int tid = threadIdx.x;
    __shared__ float hu[1536];
    for (int i = tid; i < 1536; i += 256) {
        float s = 0.f;
        for (int nc = 0; nc < 16; nc++)
            s += part[((size_t)b * 16 + nc) * 1536 + i];
        hu[i] = s;
    }
    __syncthreads();
    int nn0 = ch * 128;
    for (int i = tid; i < cT * 128; i += 256) {
        int t = i / 128, nn = nn0 + (i % 128);
        float s = 0.f;
        #pragma unroll
        for (int f = 0; f < 64; f++) s += hu[f * cT + t] * U2[(size_t)f * cN + nn];
        lhs_t[((size_t)b * cT + t) * cN + nn] = s;
    }
}

// ---------------------------------------------------------------------------
// rhs_t from bf16 h
__global__ __launch_bounds__(64) void k_rhs_t(
    const unsigned short* __restrict__ h, const float* __restrict__ U3,
    float* __restrict__ rhs_t)
{
    int bn = blockIdx.x;
    int f = threadIdx.x;
    __shared__ float sl[64][25];
    const u16x8* hp = (const u16x8*)(h + (size_t)bn * cFT + f * cT);
    float u = U3[f];
    #pragma unroll
    for (int v8 = 0; v8 < 3; v8++) {
        u16x8 hv = hp[v8];
        #pragma unroll
        for (int e = 0; e < 8; e++)
            sl[f][v8 * 8 + e] = u * bf2f(hv[e]);
    }
    __syncthreads();
    if (f < cT) {
        float s = 0.f;
        #pragma unroll
        for (int c = 0; c < 64; c++) s += sl[c][f];
        rhs_t[(size_t)bn * cT + f] = s;
    }
}

// ---------------------------------------------------------------------------
// rhs_t[b] staged in LDS (512x24 f32 = 48KB)
__global__ __launch_bounds__(576) void k_E(
    const float* __restrict__ lhs_t, const float* __restrict__ rhs_t,
    const float* __restrict__ be, const float* __restrict__ Ve,
    float* __restrict__ E)
{
    int b = blockIdx.x;
    int tid = threadIdx.x;
    int i = tid / 24, j = tid % 24;
    __shared__ float rs[12288];
    __shared__ float ps[24][25];
    __shared__ float er[24][25];
    __shared__ float mrow[24], srow[24];
    const float* rp = rhs_t + (size_t)b * 12288;
    for (int v = tid; v < 12288; v += 576) rs[v] = rp[v];
    __syncthreads();
    const float* lp = lhs_t + ((size_t)b * cT + i) * cN;
    float s = 0.f;
    for (int n = 0; n < cN; n++) s += lp[n] * rs[n * cT + j];
    s += be[i * cT + j];
    ps[i][j] = 1.f / (1.f + expf(-s));
    __syncthreads();
    float e = 0.f;
    #pragma unroll
    for (int ss = 0; ss < cT; ss++) e += Ve[i * cT + ss] * ps[ss][j];
    er[i][j] = e;
    __syncthreads();
    if (j == 0) {
        float m = -1e30f;
        for (int r = 0; r < cT; r++) m = fmaxf(m, er[i][r]);
        float sm = 0.f;
        for (int r = 0; r < cT; r++) sm += expf(er[i][r] - m);
        mrow[i] = m;
        srow[i] = sm;
    }
    __syncthreads();
    E[(size_t)b * cT * cT + i * cT + j] = expf(er[i][j] - mrow[i]) / srow[i];
}

// ---------------------------------------------------------------------------
// MFMA temporal mixing: hT[b,n,so,f] = sum_t h[b,n,f,t] * E[b][t][so].
__global__ __launch_bounds__(256) void k_tmix_mfma(
    const unsigned short* __restrict__ h,   // hbf [b,n,f,t] bf16
    const float* __restrict__ E,            // [b][24][24]
    unsigned short* __restrict__ hT)        // [b,n,t,f] bf16
{
    __shared__ float Es[24][25];
    __shared__ unsigned short bounce[8][24][64];
    int tid = threadIdx.x;
    int blk = blockIdx.x;            // 2048
    int b = blk >> 6;
    int n0 = (blk & 63) * 8;
    for (int i = tid; i < 576; i += 256)
        Es[i / 24][i % 24] = E[(size_t)b * 576 + i];
    __syncthreads();

    int lane = tid & 63, w = tid >> 6;
    int fr = lane & 15, g = lane >> 4;

    s16x8 afr[2];
    #pragma unroll
    for (int m = 0; m < 2; m++) {
        int so = m * 16 + fr;
        u16x8 a = {};
        if (so < 24 && g < 3) {
            #pragma unroll
            for (int e = 0; e < 8; e++)
                a[e] = f2bf(Es[g * 8 + e][so]);
        }
        afr[m] = *(s16x8*)&a;
    }

    f32x4 zero = {};
    #pragma unroll
    for (int ss = 0; ss < 2; ss++) {
        int s = w * 2 + ss;
        const unsigned short* hp = h + ((size_t)b * cN + n0 + s) * cFT;
        #pragma unroll
        for (int jj = 0; jj < 4; jj++) {
            u16x8 bfrag = {};
            if (g < 3)
                bfrag = *(const u16x8*)(hp + (jj * 16 + fr) * 24 + g * 8);
            s16x8 bf = *(s16x8*)&bfrag;
            #pragma unroll
            for (int m = 0; m < 2; m++) {
                f32x4 c = __builtin_amdgcn_mfma_f32_16x16x32_bf16(
                    afr[m], bf, zero, 0, 0, 0);
                #pragma unroll
                for (int r = 0; r < 4; r++) {
                    int so = m * 16 + g * 4 + r;
                    if (so < 24)
                        bounce[s][so][jj * 16 + fr] = f2bf(c[r]);
                }
            }
        }
    }
    __syncthreads();
    unsigned short* op = hT + ((size_t)b * cN + n0) * cFT;
    #pragma unroll
    for (int it = 0; it < 6; it++) {
        int i = tid + it * 256;
        *(u16x8*)(op + i * 8) = *(const u16x8*)&bounce[0][0][i * 8];
    }
}

// ---------------------------------------------------------------------------
// MFMA conv(1,3) + bias + residual(x) + LayerNorm over F. float4 stores.
__global__ __launch_bounds__(256) void k_convmfma(
    const unsigned short* __restrict__ hT,   // [b,n,t,f] bf16
    const float* __restrict__ x,             // [b,n,c,t] f32
    const unsigned short* __restrict__ W2g,  // [f][192] bf16, k=(d*64+fi)
    const float* __restrict__ cb,
    const float* __restrict__ lnw, const float* __restrict__ lnb,
    float* __restrict__ out)                 // [b,n,f,t] f32
{
    __shared__ unsigned short Hs[8][26][72];
    __shared__ unsigned short Ws[64][200];
    int tid = threadIdx.x;
    int blk = blockIdx.x;
    int b = blk >> 6;
    int n0 = (blk & 63) * 8;
    const unsigned short* hp = hT + ((size_t)b * cN + n0) * cFT;

    #pragma unroll
    for (int it = 0; it < 6; it++) {
        int v = tid + it * 256;
        int s = v / 192;
        int r = v % 192;
        int t = r >> 3, f0 = (r & 7) * 8;
        u16x8 val = *(const u16x8*)(hp + (size_t)s * cFT + t * 64 + f0);
        *(u16x8*)&Hs[s][1 + t][f0] = val;
    }
    if (tid < 144) {
        int s = tid / 18, rm = tid % 18;
        int side = rm / 9, c8 = (rm % 9) * 8;
        u16x8 z = {};
        *(u16x8*)&Hs[s][side * 25][c8] = z;
    }
    #pragma unroll
    for (int it = 0; it < 48; it++) {
        int i = tid + it * 256;
        Ws[i / 192][i % 192] = W2g[i];
    }
    __syncthreads();

    int lane = tid & 63, w = tid >> 6;
    int fr = lane & 15, kgrp = lane >> 4;
    f32x4 acc[3][4] = {};

    int sA[3], tA[3];
    #pragma unroll
    for (int mi = 0; mi < 3; mi++) {
        int row = (w * 3 + mi) * 16 + fr;
        sA[mi] = row / 24; tA[mi] = row % 24;
    }
    #pragma unroll
    for (int ks = 0; ks < 6; ks++) {
        int d = ks >> 1;
        int fi0 = (ks & 1) * 32 + kgrp * 8;
        s16x8 bf[4];
        #pragma unroll
        for (int j = 0; j < 4; j++)
            bf[j] = *(const s16x8*)&Ws[j * 16 + fr][ks * 32 + kgrp * 8];
        #pragma unroll
        for (int mi = 0; mi < 3; mi++) {
            s16x8 af = *(const s16x8*)&Hs[sA[mi]][tA[mi] + d][fi0];
            #pragma unroll
            for (int j = 0; j < 4; j++)
                acc[mi][j] = __builtin_amdgcn_mfma_f32_16x16x32_bf16(
                    af, bf[j], acc[mi][j], 0, 0, 0);
        }
    }

    float lnw_v[4], lnb_v[4], cb_v[4];
    #pragma unroll
    for (int j = 0; j < 4; j++) {
        int f = j * 16 + fr;
        lnw_v[j] = lnw[f]; lnb_v[j] = lnb[f]; cb_v[j] = cb[f];
    }
    #pragma unroll
    for (int mi = 0; mi < 3; mi++) {
        int rowbase = (w * 3 + mi) * 16 + kgrp * 4;
        int sB = rowbase / 24, tb = rowbase % 24;
        size_t slab = ((size_t)b * cN + n0 + sB) * 64;
        float outv[4][4];   // [j][r]
        #pragma unroll
        for (int r = 0; r < 4; r++) {
            int t = tb + r;
            float v[4], s1 = 0.f, s2 = 0.f;
            #pragma unroll
            for (int j = 0; j < 4; j++) {
                float xres = x[(slab + j * 16 + fr) * 24 + t];
                v[j] = acc[mi][j][r] + cb_v[j] + xres;
                s1 += v[j];
                s2 += v[j] * v[j];
            }
            #pragma unroll
            for (int off = 1; off < 16; off <<= 1) {
                s1 += __shfl_xor(s1, off, 64);
                s2 += __shfl_xor(s2, off, 64);
            }
            float mean = s1 * (1.f / 64.f);
            float var = s2 * (1.f / 64.f) - mean * mean;
            float rstd = rsqrtf(var + 1e-5f);
            #pragma unroll
            for (int j = 0; j < 4; j++)
                outv[j][r] = (v[j] - mean) * rstd * lnw_v[j] + lnb_v[j];
        }
        #pragma unroll
        for (int j = 0; j < 4; j++) {
            float4 o = make_float4(outv[j][0], outv[j][1], outv[j][2], outv[j][3]);
            *(float4*)&out[(slab + j * 16 + fr) * 24 + tb] = o;
        }
    }
}

// ---------------------------------------------------------------------------
extern "C" void kernel_launch(void* const* d_in, const int* in_sizes, int n_in,
                              void* d_out, int out_size, void* d_ws, size_t ws_size,
                              hipStream_t stream)
{
    const float* x     = (const float*)d_in[0];
    const float* cheb  = (const float*)d_in[1];
    const float* W1    = (const float*)d_in[2];
    const float* W2    = (const float*)d_in[3];
    const float* W3    = (const float*)d_in[4];
    const float* bs    = (const float*)d_in[5];
    const float* Vs    = (const float*)d_in[6];
    const float* U1    = (const float*)d_in[7];
    const float* U2    = (const float*)d_in[8];
    const float* U3    = (const float*)d_in[9];
    const float* be    = (const float*)d_in[10];
    const float* Ve    = (const float*)d_in[11];
    const float* Theta = (const float*)d_in[12];
    const float* cw    = (const float*)d_in[13];
    const float* cbp   = (const float*)d_in[14];
    const float* lnw   = (const float*)d_in[15];
    const float* lnb   = (const float*)d_in[16];
    float* out = (float*)d_out;
    float* ws  = (float*)d_ws;

    // workspace layout: round-17 layout (peak ws 138.5 MB).
    unsigned short* Vs_bf   = (unsigned short*)(ws);              // 131072 f32
    unsigned short* cheb_bf = (unsigned short*)(ws + 131072);     // 393216 f32
    float*  lhs  = ws + 524288;     // 393216 (also lhs_t)
    float*  rhs  = ws + 917504;     // 393216 (also rhs_t)
    float*  part = ws + 1310720;    // 786432
    unsigned short* ThT = (unsigned short*)(ws + 1310720);        // overlays part
    float*  Ebuf = ws + 2097152;    // 18432
    unsigned short* W2g = (unsigned short*)(ws + 2115584);        // 12288 u16
    unsigned short* St  = (unsigned short*)(ws + 2124800);        // 8388608 u16
    unsigned short* Wk  = (unsigned short*)(ws + 6319104);        // 12582912 u16, [zz][k][512][512]
    unsigned short* XTt = (unsigned short*)(ws + 12610560);       // 37748736 u16
    unsigned short* Pt  = (unsigned short*)(ws + 12610560);       // overlay (dead before XTt)
    float*          S0  = ws + 22047744;                          // 8388608 f32 (dead before XTt)
    unsigned short* xT2 = (unsigned short*)(ws + 31484928);       // 6291456 u16 (per half)
    unsigned short* hbf = (unsigned short*)out;                   // 25165824 u16 = 50 MB of d_out
    unsigned short* hT  = XTt;                                    // reuse after GEMM loop

    const long long NN2 = (long long)cN * cN;        // 262144
    const long long NFT = (long long)cN * cFT;       // 786432
    const long long segX = 16LL * 1536 * 512;        // XTt k-segment

    k_convert<<<1024, 256, 0, stream>>>(Vs, Vs_bf, 262144);
    k_convert<<<3072, 256, 0, stream>>>(cheb, cheb_bf, 786432);
    k_wprep<<<48, 256, 0, stream>>>(cw, W2g);
    k_thprep<<<48, 256, 0, stream>>>(Theta, ThT);

    // spatial attention
    k_spatial_lr<<<cB * cN / 4, 256, 0, stream>>>(x, W1, W2, W3, lhs, rhs);
    k_product_t<<<dim3(32, 32, cB), dim3(16, 16), 0, stream>>>(lhs, rhs, bs, Pt);
    // S0 = Vs @ P: 512 blocks (1-D swizzled)
    k_mfma_gemm<0><<<512, 256, 0, stream>>>(
        Vs_bf, 512, 0LL, 0LL, Pt, 512, NN2, 0LL, S0, 512, NN2, 512, 0, 0, 4, 4);
    k_softmax512<<<cB * cN, 256, 0, stream>>>(S0);
    k_transpose_S<<<dim3(8, 8, cB), 256, 0, stream>>>(S0, St);

    // Cheb conv, batch-halved with fused-K final GEMM -> h (bf16+relu) in d_out
    for (int half = 0; half < 2; half++) {
        k_xtrans_half<<<16 * 512, 64, 0, stream>>>(x, half, xT2);
        k_xtheta_mfma<<<dim3(4, 24, 16), 256, 0, stream>>>(xT2, ThT, XTt, segX);
        // W' = cheb'(1536x512) @ S_half: merged GEMM, 768 blocks
        k_mfma_gemm<1><<<768, 256, 0, stream>>>(
            cheb_bf, 512, 0LL, 0LL,
            St + (size_t)half * 16 * NN2, 512, NN2, 0LL,
            Wk, 512, 3 * NN2, 512, 0, 0, 4, 12);
        // h_half = relu(sum_k W_k @ XT_k): K=1536 segmented
        k_mfma_gemm<1><<<768, 256, 0, stream>>>(
            Wk, 512, 3 * NN2, NN2, XTt, 512, 786432LL, segX,
            hbf + (size_t)half * 16 * NFT, 1536, NFT, 1536, 0, 1, 12, 4);
    }

    // temporal attention (reads h = hbf bf16; ThT dead from here)
    k_hU1_part<<<dim3(cB, 16), 256, 0, stream>>>(hbf, U1, part);
    k_rhs_t<<<cB * cN, 64, 0, stream>>>(hbf, U3, rhs);
    k_lhs_t<<<dim3(cB, 4), 256, 0, stream>>>(part, U2, lhs);
    k_E<<<cB, 576, 0, stream>>>(lhs, rhs, be, Ve, Ebuf);

    // temporal mixing via MFMA -> hT (bf16, [t,f]; hbf dead after), conv+LN -> out
    k_tmix_mfma<<<2048, 256, 0, stream>>>(hbf, Ebuf, hT);
    k_convmfma<<<2048, 256, 0, stream>>>(hT, x, W2g, cbp, lnw, lnb, out);
}